// Round 5
// baseline (682.789 us; speedup 1.0000x reference)
//
#include <hip/hip_runtime.h>
#include <math.h>

#define NUM_USERS 200000
#define NUM_PRODUCTS 100000
#define N_NODES 300000
#define N_EDGES 1000000
#define EDIM 64
#define FDIM 128
#define CAP 40            // fixed adjacency capacity/node; max degree ~27 (Poisson(10) tail)
#define LDST 72           // LDS tile row stride in u16 (144 B: 16B-aligned, breaks pow2 banks)
#define NT_U 12500        // user tiles
#define NT_ALL 18750      // total node tiles
#define ZERO_BLK 1173     // 1173*256 = 300288 >= 300032 cnt + 80 bucket counters
#define NBUK 80           // CSR bins: dest in [0,200000), 2500 nodes/bucket (400KB adj region)
#define BNODES 2500
#define BINCAP 49152      // max bucket load ~37.5K entries; 80*49152*8B = 31.5MB (overlays xbuf)
#define CSR_REP 4         // blocks per bucket in k_csr (XCD-affine)

typedef __attribute__((ext_vector_type(8))) short short8;   // 8 bf16 in 4 VGPRs
typedef __attribute__((ext_vector_type(4))) float f32x4;    // MFMA accumulator

// fp32 -> bf16 round-to-nearest-even
static __device__ inline short f2bf(float f) {
    unsigned int u = __float_as_uint(f);
    unsigned int r = (u + 0x7FFFu + ((u >> 16) & 1u)) >> 16;
    return (short)r;
}
static __device__ inline float bf2f(unsigned short s) {
    return __uint_as_float(((unsigned int)s) << 16);
}
// deg^-1/2 with self-loop; same v_rsq_f32 the old k_dis used -> bit-identical numerics
static __device__ inline float disf(int c) {
    return rsqrtf(1.0f + (float)c);
}

// ---------------- setup: zero cnt + bucket counters + weight prep ----------------
// wts layout (shorts): WufT@0(8192) WpfT@8192(8192) c1T@16384(4096) c2T@20480(4096) W1T@24576(8192)
__global__ void k_setup(int* __restrict__ cnt,
                        const float* __restrict__ W_uf, const float* __restrict__ W_pf,
                        const float* __restrict__ c1, const float* __restrict__ c2,
                        const float* __restrict__ W1, short* __restrict__ wts) {
    int b = blockIdx.x;
    if (b < ZERO_BLK) {
        int i = b * 256 + threadIdx.x;
        if (i < 300032 + NBUK) cnt[i] = 0;   // cnt + gbin_cnt (contiguous)
        return;
    }
    int gid = (b - ZERO_BLK) * 256 + threadIdx.x;
    if (gid >= 32768) return;
    if (gid < 8192) {
        int n = gid >> 7, k = gid & 127;
        wts[gid] = f2bf(W_uf[k * 64 + n]);
    } else if (gid < 16384) {
        int i = gid - 8192; int n = i >> 7, k = i & 127;
        wts[gid] = f2bf(W_pf[k * 64 + n]);
    } else if (gid < 20480) {
        int i = gid - 16384; int n = i >> 6, k = i & 63;
        wts[gid] = f2bf(c1[k * 64 + n]);
    } else if (gid < 24576) {
        int i = gid - 20480; int n = i >> 6, k = i & 63;
        wts[gid] = f2bf(c2[k * 64 + n]);
    } else {
        int i = gid - 24576; int n = i >> 7, k = i & 127;
        wts[gid] = f2bf(W1[k * 64 + n]);
    }
}

// ---------------- CSR phase 1: LDS-binned edge scatter into per-bucket streams ----------------
__global__ __launch_bounds__(256) void k_bin(
    const int* __restrict__ ei, int* __restrict__ gcnt, int* __restrict__ gbin) {
    __shared__ int lcnt[NBUK];
    __shared__ int lbase[NBUK];
    int tid = threadIdx.x;
    if (tid < NBUK) lcnt[tid] = 0;
    __syncthreads();
    int e0 = (blockIdx.x * 256 + tid) * 4;
    bool act = e0 < N_EDGES;
    int d[8], s[8], rk[8], bk[8];
    if (act) {
        int4 uu = *(const int4*)(ei + e0);            // user ids
        int4 pp = *(const int4*)(ei + N_EDGES + e0);  // raw (un-offset) product ids — reference quirk
        d[0] = pp.x; s[0] = uu.x;  d[1] = uu.x; s[1] = pp.x;
        d[2] = pp.y; s[2] = uu.y;  d[3] = uu.y; s[3] = pp.y;
        d[4] = pp.z; s[4] = uu.z;  d[5] = uu.z; s[5] = pp.z;
        d[6] = pp.w; s[6] = uu.w;  d[7] = uu.w; s[7] = pp.w;
#pragma unroll
        for (int j = 0; j < 8; ++j) {
            bk[j] = d[j] / BNODES;                    // dest < 200000 always
            rk[j] = atomicAdd(&lcnt[bk[j]], 1);
        }
    }
    __syncthreads();
    if (tid < NBUK) lbase[tid] = atomicAdd(&gcnt[tid], lcnt[tid]);
    __syncthreads();
    if (act) {
#pragma unroll
        for (int j = 0; j < 8; ++j) {
            int pos = lbase[bk[j]] + rk[j];
            if (pos < BINCAP)                         // safety guard (expected max ~38K << 49152)
                *(int2*)(gbin + ((size_t)bk[j] * BINCAP + pos) * 2) = make_int2(d[j], s[j]);
        }
    }
}

// ---------------- CSR phase 2: per-bucket slot assignment, XCD-affine for L2 write merging ----------------
__global__ __launch_bounds__(256) void k_csr(
    const int* __restrict__ gcnt, const int* __restrict__ gbin,
    int* __restrict__ cnt, int* __restrict__ adj) {
    int i = blockIdx.x;
    int xcd = i & 7, k = i >> 3;              // blockIdx%8 ~ XCD (round-robin dispatch heuristic)
    int bucket = (k % (NBUK / 8)) * 8 + xcd;  // interleave heavy (dest<100K) buckets across XCDs
    int rep = k / (NBUK / 8);                 // [0, CSR_REP)
    int n = gcnt[bucket];
    const int* bb = gbin + (size_t)bucket * BINCAP * 2;
    const int stride = CSR_REP * 256;
    int idx = rep * 256 + threadIdx.x;
    for (; idx + 3 * stride < n; idx += 4 * stride) {   // 4 independent atomic round-trips in flight
        int2 e0 = *(const int2*)(bb + (size_t)(idx)*2);
        int2 e1 = *(const int2*)(bb + (size_t)(idx + stride) * 2);
        int2 e2 = *(const int2*)(bb + (size_t)(idx + 2 * stride) * 2);
        int2 e3 = *(const int2*)(bb + (size_t)(idx + 3 * stride) * 2);
        int s0 = atomicAdd(&cnt[e0.x], 1);
        int s1 = atomicAdd(&cnt[e1.x], 1);
        int s2 = atomicAdd(&cnt[e2.x], 1);
        int s3 = atomicAdd(&cnt[e3.x], 1);
        adj[(size_t)e0.x * CAP + s0] = e0.y;
        adj[(size_t)e1.x * CAP + s1] = e1.y;
        adj[(size_t)e2.x * CAP + s2] = e2.y;
        adj[(size_t)e3.x * CAP + s3] = e3.y;
    }
    for (; idx < n; idx += stride) {
        int2 e = *(const int2*)(bb + (size_t)idx * 2);
        int s = atomicAdd(&cnt[e.x], 1);
        adj[(size_t)e.x * CAP + s] = e.y;
    }
}

// ---------------- FUSED: x0 = feat@W + b + emb; h1' = dis*(x0@c1W) ----------------
// v2: all global loads hoisted (8x dwordx4 feat + 16 emb + 4 cnt in flight), VGPR cap 256
// so B-frags stay resident; no __syncthreads (each wave owns lds[wave] — intra-wave only).
__global__ __launch_bounds__(256, 2) void k_xform_c1(
    const float* __restrict__ user_feat, const float* __restrict__ prod_feat,
    const short* __restrict__ wts,
    const float* __restrict__ b_uf, const float* __restrict__ b_pf,
    const float* __restrict__ user_emb, const float* __restrict__ prod_emb,
    const int* __restrict__ cnt, unsigned short* __restrict__ h) {
    __shared__ unsigned short lds[4][16 * LDST];
    int tid = threadIdx.x;
    int wave = tid >> 6;
    int tile = blockIdx.x * 4 + wave;
    if (tile >= NT_ALL) return;              // no barrier in kernel -> early exit safe
    int lane = tid & 63, ln = lane & 15, quad = lane >> 4;

    // per-wave operand selection (uniform within wave -> no divergence)
    const float* feat; const short* WT; const float* b; const float* emb;
    int node_off, mtile;
    if (tile < NT_U) {
        feat = user_feat; WT = wts;        b = b_uf; emb = user_emb; node_off = 0;         mtile = tile;
    } else {
        feat = prod_feat; WT = wts + 8192; b = b_pf; emb = prod_emb; node_off = NUM_USERS; mtile = tile - NT_U;
    }
    const short* c1T = wts + 16384;
    int mbase = mtile * 16;

    // ---- hoist ALL global loads: feat (8 dwordx4), emb (16 dword), cnt (4 dword) ----
    const float* arow = feat + (size_t)(mbase + ln) * FDIM + quad * 8;
    float4 fl[4], fh[4];
#pragma unroll
    for (int kk = 0; kk < 4; ++kk) {
        fl[kk] = *(const float4*)(arow + kk * 32);
        fh[kk] = *(const float4*)(arow + kk * 32 + 4);
    }
    float ev[4][4];                           // [r][t]
#pragma unroll
    for (int r = 0; r < 4; ++r)
#pragma unroll
        for (int t = 0; t < 4; ++t)
            ev[r][t] = emb[(size_t)(mbase + quad * 4 + r) * EDIM + t * 16 + ln];
    int cdv[4];
#pragma unroll
    for (int r = 0; r < 4; ++r) cdv[r] = cnt[node_off + mbase + quad * 4 + r];

    short8 Bx[4][4];
#pragma unroll
    for (int t = 0; t < 4; ++t)
#pragma unroll
        for (int kk = 0; kk < 4; ++kk)
            Bx[t][kk] = *(const short8*)(WT + ((t * 16 + ln) * 128 + kk * 32 + quad * 8));
    short8 Bc[4][2];
#pragma unroll
    for (int t = 0; t < 4; ++t)
#pragma unroll
        for (int kk = 0; kk < 2; ++kk)
            Bc[t][kk] = *(const short8*)(c1T + ((t * 16 + ln) * 64 + kk * 32 + quad * 8));
    float bv[4];
#pragma unroll
    for (int t = 0; t < 4; ++t) bv[t] = b[t * 16 + ln];

    // ---- GEMM1: x0 = feat @ W ----
    f32x4 acc[4] = {{0.f,0.f,0.f,0.f},{0.f,0.f,0.f,0.f},{0.f,0.f,0.f,0.f},{0.f,0.f,0.f,0.f}};
#pragma unroll
    for (int kk = 0; kk < 4; ++kk) {
        short8 Af;
        Af[0] = f2bf(fl[kk].x); Af[1] = f2bf(fl[kk].y); Af[2] = f2bf(fl[kk].z); Af[3] = f2bf(fl[kk].w);
        Af[4] = f2bf(fh[kk].x); Af[5] = f2bf(fh[kk].y); Af[6] = f2bf(fh[kk].z); Af[7] = f2bf(fh[kk].w);
#pragma unroll
        for (int t = 0; t < 4; ++t)
            acc[t] = __builtin_amdgcn_mfma_f32_16x16x32_bf16(Af, Bx[t][kk], acc[t], 0, 0, 0);
    }
    // x0 epilogue -> LDS tile (bf16, same quantization the old memory round-trip applied)
#pragma unroll
    for (int r = 0; r < 4; ++r)
#pragma unroll
        for (int t = 0; t < 4; ++t) {
            float v = acc[t][r] + bv[t] + ev[r][t];
            lds[wave][(quad * 4 + r) * LDST + t * 16 + ln] = (unsigned short)f2bf(v);
        }
    // intra-wave LDS dependency only: lgkmcnt ordering suffices, no barrier
    // ---- GEMM2: h1' = dis * (x0 @ c1W) ----
    f32x4 acch[4] = {{0.f,0.f,0.f,0.f},{0.f,0.f,0.f,0.f},{0.f,0.f,0.f,0.f},{0.f,0.f,0.f,0.f}};
#pragma unroll
    for (int kk = 0; kk < 2; ++kk) {
        short8 Af = *(const short8*)(&lds[wave][ln * LDST + kk * 32 + quad * 8]);
#pragma unroll
        for (int t = 0; t < 4; ++t)
            acch[t] = __builtin_amdgcn_mfma_f32_16x16x32_bf16(Af, Bc[t][kk], acch[t], 0, 0, 0);
    }
    float disv[4];
#pragma unroll
    for (int r = 0; r < 4; ++r) disv[r] = disf(cdv[r]);
#pragma unroll
    for (int r = 0; r < 4; ++r) {
        int node = mbase + quad * 4 + r;
#pragma unroll
        for (int t = 0; t < 4; ++t)
            h[(size_t)(node_off + node) * EDIM + t * 16 + ln] =
                (unsigned short)f2bf(disv[r] * acch[t][r]);
    }
}

// ---------------- FUSED: x1 = relu(dis*(h1'[d]+Σ h1'[src]) + b1); h2' = dis*(x1@c2W) ----------------
__global__ __launch_bounds__(256) void k_gather_c2(
    const int* __restrict__ adj, const int* __restrict__ cnt,
    const unsigned short* __restrict__ h,
    const float* __restrict__ b1, const short* __restrict__ c2T,
    unsigned short* __restrict__ hout) {
    __shared__ unsigned short lds[4][16 * LDST];
    int tid = threadIdx.x;
    int wave = tid >> 6;
    int tile = blockIdx.x * 4 + wave;
    if (tile >= N_NODES / 16) return;        // no barrier in kernel -> early exit safe
    int lane = tid & 63, ln = lane & 15, quad = lane >> 4;
    const unsigned int* hp = (const unsigned int*)h;    // bf16x2 view, row stride 32

    short8 Bc[4][2];
#pragma unroll
    for (int t = 0; t < 4; ++t)
#pragma unroll
        for (int kk = 0; kk < 2; ++kk)
            Bc[t][kk] = *(const short8*)(c2T + ((t * 16 + ln) * 64 + kk * 32 + quad * 8));

    int mbase = tile * 16;
    float2 bb0 = ((const float2*)b1)[ln];        // feats 2ln, 2ln+1
    float2 bb1 = ((const float2*)b1)[16 + ln];   // feats 32+2ln, 32+2ln+1

#pragma unroll 1
    for (int it = 0; it < 4; ++it) {
        int d = mbase + it * 4 + quad;
        const unsigned int* hrow = hp + (size_t)d * 32;
        unsigned int s0 = hrow[ln], s1 = hrow[16 + ln];          // self-loop term
        float a0 = bf2f((unsigned short)s0);
        float a1 = bf2f((unsigned short)(s0 >> 16));
        float a2 = bf2f((unsigned short)s1);
        float a3 = bf2f((unsigned short)(s1 >> 16));
        int cd = cnt[d];
        const int* ap = adj + (size_t)d * CAP;
        int i = 0;
        for (; i + 1 < cd; i += 2) {                             // 4 gathers in flight/lane
            int r0 = ap[i], r1 = ap[i + 1];
            unsigned int p00 = hp[(size_t)r0 * 32 + ln];
            unsigned int p01 = hp[(size_t)r0 * 32 + 16 + ln];
            unsigned int p10 = hp[(size_t)r1 * 32 + ln];
            unsigned int p11 = hp[(size_t)r1 * 32 + 16 + ln];
            a0 += bf2f((unsigned short)p00) + bf2f((unsigned short)p10);
            a1 += bf2f((unsigned short)(p00 >> 16)) + bf2f((unsigned short)(p10 >> 16));
            a2 += bf2f((unsigned short)p01) + bf2f((unsigned short)p11);
            a3 += bf2f((unsigned short)(p01 >> 16)) + bf2f((unsigned short)(p11 >> 16));
        }
        if (i < cd) {
            int r0 = ap[i];
            unsigned int p00 = hp[(size_t)r0 * 32 + ln];
            unsigned int p01 = hp[(size_t)r0 * 32 + 16 + ln];
            a0 += bf2f((unsigned short)p00);
            a1 += bf2f((unsigned short)(p00 >> 16));
            a2 += bf2f((unsigned short)p01);
            a3 += bf2f((unsigned short)(p01 >> 16));
        }
        float dv = disf(cd);
        float v0 = fmaxf(fmaf(dv, a0, bb0.x), 0.f);
        float v1 = fmaxf(fmaf(dv, a1, bb0.y), 0.f);
        float v2 = fmaxf(fmaf(dv, a2, bb1.x), 0.f);
        float v3 = fmaxf(fmaf(dv, a3, bb1.y), 0.f);
        unsigned int* lrow = (unsigned int*)&lds[wave][(it * 4 + quad) * LDST];
        lrow[ln] = ((unsigned int)(unsigned short)f2bf(v1) << 16)
                 | (unsigned int)(unsigned short)f2bf(v0);
        lrow[16 + ln] = ((unsigned int)(unsigned short)f2bf(v3) << 16)
                      | (unsigned int)(unsigned short)f2bf(v2);
    }
    // intra-wave LDS dependency only: no barrier needed
    // h2' = dis * (x1 @ c2W)
    f32x4 acc[4] = {{0.f,0.f,0.f,0.f},{0.f,0.f,0.f,0.f},{0.f,0.f,0.f,0.f},{0.f,0.f,0.f,0.f}};
#pragma unroll
    for (int kk = 0; kk < 2; ++kk) {
        short8 Af = *(const short8*)(&lds[wave][ln * LDST + kk * 32 + quad * 8]);
#pragma unroll
        for (int t = 0; t < 4; ++t)
            acc[t] = __builtin_amdgcn_mfma_f32_16x16x32_bf16(Af, Bc[t][kk], acc[t], 0, 0, 0);
    }
    float disv[4];
#pragma unroll
    for (int r = 0; r < 4; ++r) disv[r] = disf(cnt[mbase + quad * 4 + r]);
#pragma unroll
    for (int r = 0; r < 4; ++r) {
        int node = mbase + quad * 4 + r;
#pragma unroll
        for (int t = 0; t < 4; ++t)
            hout[(size_t)node * EDIM + t * 16 + ln] = (unsigned short)f2bf(disv[r] * acc[t][r]);
    }
}

// ---------------- gather + finish (conv2 output): x[d] = dis[d]*(h'[d]+Σ h'[src]) + b ----------------
__global__ __launch_bounds__(256) void k_gather(
    const int* __restrict__ adj, const int* __restrict__ cnt,
    const unsigned short* __restrict__ h,
    const float* __restrict__ b, unsigned short* __restrict__ xout, int relu) {
    int d = blockIdx.x * 4 + (threadIdx.x >> 6);
    if (d >= N_NODES) return;
    int l = threadIdx.x & 63;
    int half = l >> 5, c2 = l & 31;              // feature pair c2 -> feats {2c2, 2c2+1}
    const unsigned int* hp = (const unsigned int*)h;   // bf16x2 view, row stride 32

    float ax = 0.f, ay = 0.f;
    if (half == 0) {                              // self-loop term, counted once
        unsigned int pr = hp[(size_t)d * 32 + c2];
        ax = bf2f((unsigned short)pr);
        ay = bf2f((unsigned short)(pr >> 16));
    }
    int c = cnt[d];
    const int* ap = adj + (size_t)d * CAP;
    int i = 0;
    for (; i + 3 < c; i += 4) {
        int s0 = ap[i + half];
        int s1 = ap[i + 2 + half];
        unsigned int p0 = hp[(size_t)s0 * 32 + c2];
        unsigned int p1 = hp[(size_t)s1 * 32 + c2];
        ax += bf2f((unsigned short)p0) + bf2f((unsigned short)p1);
        ay += bf2f((unsigned short)(p0 >> 16)) + bf2f((unsigned short)(p1 >> 16));
    }
    if (i + half < c) {
        unsigned int p0 = hp[(size_t)ap[i + half] * 32 + c2];
        ax += bf2f((unsigned short)p0);
        ay += bf2f((unsigned short)(p0 >> 16));
    }
    if (i + 2 + half < c) {
        unsigned int p0 = hp[(size_t)ap[i + 2 + half] * 32 + c2];
        ax += bf2f((unsigned short)p0);
        ay += bf2f((unsigned short)(p0 >> 16));
    }
    ax += __shfl_xor(ax, 32, 64);                 // combine the two halves
    ay += __shfl_xor(ay, 32, 64);
    float dv = disf(c);
    float2 bb = ((const float2*)b)[c2];
    float v0 = fmaf(dv, ax, bb.x);
    float v1 = fmaf(dv, ay, bb.y);
    if (relu) { v0 = fmaxf(v0, 0.f); v1 = fmaxf(v1, 0.f); }
    if (half == 0) {
        unsigned int pk = ((unsigned int)(unsigned short)f2bf(v1) << 16)
                        | (unsigned int)(unsigned short)f2bf(v0);
        ((unsigned int*)xout)[(size_t)d * 32 + c2] = pk;
    }
}

// ---------------- edge predictor via bf16 MFMA, ei prefetch + hoisted A loads ----------------
__global__ __launch_bounds__(256) void k_pred_mfma(
    const int* __restrict__ ei, const unsigned short* __restrict__ x,
    const short* __restrict__ W1T, const float* __restrict__ b1,
    const float* __restrict__ W2, const float* __restrict__ b2,
    float* __restrict__ preds) {
    int tid = threadIdx.x;
    int wave = tid >> 6, lane = tid & 63;
    int ln = lane & 15, quad = lane >> 4;

    short8 Bf[4][4];
#pragma unroll
    for (int t = 0; t < 4; ++t)
#pragma unroll
        for (int kk = 0; kk < 4; ++kk)
            Bf[t][kk] = *(const short8*)(W1T + ((t * 16 + ln) * 128 + kk * 32 + quad * 8));

    float b1v[4], W2v[4];
#pragma unroll
    for (int t = 0; t < 4; ++t) {
        b1v[t] = b1[t * 16 + ln];
        W2v[t] = W2[t * 16 + ln];
    }
    float b2s = b2[0];

    const int n_tiles = N_EDGES / 16;
    int gw = blockIdx.x * 4 + wave;
    int nwaves = gridDim.x * 4;

    int cu = 0, cp = 0;
    if (gw < n_tiles) {
        cu = ei[gw * 16 + ln];
        cp = ei[N_EDGES + gw * 16 + ln] + NUM_USERS;
    }
    for (int tile = gw; tile < n_tiles; tile += nwaves) {
        int u = cu, p = cp;
        int nt = tile + nwaves;
        if (nt < n_tiles) {                       // prefetch next tile's indices
            cu = ei[nt * 16 + ln];
            cp = ei[N_EDGES + nt * 16 + ln] + NUM_USERS;
        }
        short8 Af[4];                             // all 4 A loads in flight
        Af[0] = *(const short8*)(x + (size_t)u * EDIM + quad * 8);
        Af[1] = *(const short8*)(x + (size_t)u * EDIM + 32 + quad * 8);
        Af[2] = *(const short8*)(x + (size_t)p * EDIM + quad * 8);
        Af[3] = *(const short8*)(x + (size_t)p * EDIM + 32 + quad * 8);

        f32x4 acc[4] = {{0.f,0.f,0.f,0.f},{0.f,0.f,0.f,0.f},{0.f,0.f,0.f,0.f},{0.f,0.f,0.f,0.f}};
#pragma unroll
        for (int kk = 0; kk < 4; ++kk)
#pragma unroll
            for (int t = 0; t < 4; ++t)
                acc[t] = __builtin_amdgcn_mfma_f32_16x16x32_bf16(Af[kk], Bf[t][kk], acc[t], 0, 0, 0);

        float out[4];
#pragma unroll
        for (int r = 0; r < 4; ++r) {
            float part = 0.f;
#pragma unroll
            for (int t = 0; t < 4; ++t) {
                float hv = fmaxf(acc[t][r] + b1v[t], 0.f);
                part = fmaf(hv, W2v[t], part);
            }
            part += __shfl_xor(part, 1, 64);
            part += __shfl_xor(part, 2, 64);
            part += __shfl_xor(part, 4, 64);
            part += __shfl_xor(part, 8, 64);
            out[r] = part;
        }
        if (ln == 0) {
            int ebase = tile * 16;
#pragma unroll
            for (int r = 0; r < 4; ++r) {
                float logit = out[r] + b2s;
                preds[ebase + quad * 4 + r] = 5.f / (1.f + expf(-logit));
            }
        }
    }
}

extern "C" void kernel_launch(void* const* d_in, const int* in_sizes, int n_in,
                              void* d_out, int out_size, void* d_ws, size_t ws_size,
                              hipStream_t stream) {
    const int*   ei        = (const int*)d_in[0];
    const float* user_feat = (const float*)d_in[1];
    const float* prod_feat = (const float*)d_in[2];
    const float* user_emb  = (const float*)d_in[3];
    const float* prod_emb  = (const float*)d_in[4];
    const float* W_uf      = (const float*)d_in[5];
    const float* b_uf      = (const float*)d_in[6];
    const float* W_pf      = (const float*)d_in[7];
    const float* b_pf      = (const float*)d_in[8];
    const float* conv1_W   = (const float*)d_in[9];
    const float* conv1_b   = (const float*)d_in[10];
    const float* conv2_W   = (const float*)d_in[11];
    const float* conv2_b   = (const float*)d_in[12];
    const float* pred_W1   = (const float*)d_in[13];
    const float* pred_b1   = (const float*)d_in[14];
    const float* pred_W2   = (const float*)d_in[15];
    const float* pred_b2   = (const float*)d_in[16];

    // workspace layout (4-byte units)
    int* ws_i = (int*)d_ws;
    int*   cnt  = ws_i;                            // 300032 + NBUK bucket counters right after
    int*   gcnt = ws_i + 300032;                   // 80 ints (zeroed with cnt)
    int*   adj  = ws_i + 600064;                   // 300032*40 = 12,001,280
    unsigned short* xbuf = (unsigned short*)(ws_i + 12601344);  // 38.4MB; gbin overlays (dead until gather_c2)
    int*   gbin = ws_i + 12601344;                 // 80*49152 int2 entries = 31.5MB
    unsigned short* hbuf = (unsigned short*)(ws_i + 22201344);  // 38.4MB
    short* wts = (short*)(ws_i + 31801344);        // 32768 bf16
    float* preds = (float*)d_out;

    // setup (zero cnt+gcnt + weight prep), then two-phase binned CSR build
    k_setup<<<ZERO_BLK + 128, 256, 0, stream>>>(cnt, W_uf, W_pf, conv1_W, conv2_W, pred_W1, wts);
    k_bin<<<(N_EDGES / 4 + 255) / 256, 256, 0, stream>>>(ei, gcnt, gbin);
    k_csr<<<NBUK * CSR_REP, 256, 0, stream>>>(gcnt, gbin, cnt, adj);

    // fused node-transform + conv1 GEMM (users+products, one dispatch) -> hbuf = h1'
    k_xform_c1<<<(NT_ALL + 3) / 4, 256, 0, stream>>>(user_feat, prod_feat, wts,
                                                     b_uf, b_pf, user_emb, prod_emb,
                                                     cnt, hbuf);

    // fused conv1-gather + conv2 GEMM -> xbuf = h2' (gbin dead from here); x1 never hits memory
    k_gather_c2<<<(18750 + 3) / 4, 256, 0, stream>>>(adj, cnt, hbuf, conv1_b,
                                                     wts + 20480, xbuf);
    // conv2 gather -> hbuf = x2 (final node embeddings)
    k_gather<<<N_NODES / 4, 256, 0, stream>>>(adj, cnt, xbuf, conv2_b, hbuf, 0);

    // predictor
    k_pred_mfma<<<2048, 256, 0, stream>>>(ei, hbuf, wts + 24576, pred_b1, pred_W2, pred_b2, preds);
}

// Round 6
// 680.189 us; speedup vs baseline: 1.0038x; 1.0038x over previous
//
#include <hip/hip_runtime.h>
#include <math.h>

#define NUM_USERS 200000
#define NUM_PRODUCTS 100000
#define N_NODES 300000
#define N_EDGES 1000000
#define EDIM 64
#define FDIM 128
#define CAP 40            // fixed adjacency capacity/node; max degree ~27 (Poisson(10) tail)
#define LDST 72           // LDS tile row stride in u16 (144 B: 16B-aligned, breaks pow2 banks)
#define NT_U 12500        // user tiles
#define NT_ALL 18750      // total node tiles
#define ZERO_BLK 1173     // 1173*256 = 300288 >= 300032 cnt + 80 bucket counters
#define NBUK 80           // CSR bins: dest in [0,200000), 2500 nodes/bucket (400KB adj region)
#define BNODES 2500
#define BINCAP 49152      // max bucket load ~37.5K entries; 80*49152*8B = 31.5MB (overlays xbuf)
#define CSR_REP 4         // blocks per bucket in k_csr (XCD-affine)

typedef __attribute__((ext_vector_type(8))) short short8;   // 8 bf16 in 4 VGPRs
typedef __attribute__((ext_vector_type(4))) float f32x4;    // MFMA accumulator

// fp32 -> bf16 round-to-nearest-even
static __device__ inline short f2bf(float f) {
    unsigned int u = __float_as_uint(f);
    unsigned int r = (u + 0x7FFFu + ((u >> 16) & 1u)) >> 16;
    return (short)r;
}
static __device__ inline float bf2f(unsigned short s) {
    return __uint_as_float(((unsigned int)s) << 16);
}
// deg^-1/2 with self-loop; same v_rsq_f32 the old k_dis used -> bit-identical numerics
static __device__ inline float disf(int c) {
    return rsqrtf(1.0f + (float)c);
}

// ---------------- setup: zero cnt + bucket counters + weight prep ----------------
// wts layout (shorts): WufT@0(8192) WpfT@8192(8192) c1T@16384(4096) c2T@20480(4096) W1T@24576(8192)
__global__ void k_setup(int* __restrict__ cnt,
                        const float* __restrict__ W_uf, const float* __restrict__ W_pf,
                        const float* __restrict__ c1, const float* __restrict__ c2,
                        const float* __restrict__ W1, short* __restrict__ wts) {
    int b = blockIdx.x;
    if (b < ZERO_BLK) {
        int i = b * 256 + threadIdx.x;
        if (i < 300032 + NBUK) cnt[i] = 0;   // cnt + gbin_cnt (contiguous)
        return;
    }
    int gid = (b - ZERO_BLK) * 256 + threadIdx.x;
    if (gid >= 32768) return;
    if (gid < 8192) {
        int n = gid >> 7, k = gid & 127;
        wts[gid] = f2bf(W_uf[k * 64 + n]);
    } else if (gid < 16384) {
        int i = gid - 8192; int n = i >> 7, k = i & 127;
        wts[gid] = f2bf(W_pf[k * 64 + n]);
    } else if (gid < 20480) {
        int i = gid - 16384; int n = i >> 6, k = i & 63;
        wts[gid] = f2bf(c1[k * 64 + n]);
    } else if (gid < 24576) {
        int i = gid - 20480; int n = i >> 6, k = i & 63;
        wts[gid] = f2bf(c2[k * 64 + n]);
    } else {
        int i = gid - 24576; int n = i >> 7, k = i & 127;
        wts[gid] = f2bf(W1[k * 64 + n]);
    }
}

// ---------------- CSR phase 1: LDS-binned edge scatter into per-bucket streams ----------------
__global__ __launch_bounds__(256) void k_bin(
    const int* __restrict__ ei, int* __restrict__ gcnt, int* __restrict__ gbin) {
    __shared__ int lcnt[NBUK];
    __shared__ int lbase[NBUK];
    int tid = threadIdx.x;
    if (tid < NBUK) lcnt[tid] = 0;
    __syncthreads();
    int e0 = (blockIdx.x * 256 + tid) * 4;
    bool act = e0 < N_EDGES;
    int d[8], s[8], rk[8], bk[8];
    if (act) {
        int4 uu = *(const int4*)(ei + e0);            // user ids
        int4 pp = *(const int4*)(ei + N_EDGES + e0);  // raw (un-offset) product ids — reference quirk
        d[0] = pp.x; s[0] = uu.x;  d[1] = uu.x; s[1] = pp.x;
        d[2] = pp.y; s[2] = uu.y;  d[3] = uu.y; s[3] = pp.y;
        d[4] = pp.z; s[4] = uu.z;  d[5] = uu.z; s[5] = pp.z;
        d[6] = pp.w; s[6] = uu.w;  d[7] = uu.w; s[7] = pp.w;
#pragma unroll
        for (int j = 0; j < 8; ++j) {
            bk[j] = d[j] / BNODES;                    // dest < 200000 always
            rk[j] = atomicAdd(&lcnt[bk[j]], 1);
        }
    }
    __syncthreads();
    if (tid < NBUK) lbase[tid] = atomicAdd(&gcnt[tid], lcnt[tid]);
    __syncthreads();
    if (act) {
#pragma unroll
        for (int j = 0; j < 8; ++j) {
            int pos = lbase[bk[j]] + rk[j];
            if (pos < BINCAP)                         // safety guard (expected max ~38K << 49152)
                *(int2*)(gbin + ((size_t)bk[j] * BINCAP + pos) * 2) = make_int2(d[j], s[j]);
        }
    }
}

// ---------------- CSR phase 2: per-bucket slot assignment, XCD-affine for L2 write merging ----------------
__global__ __launch_bounds__(256) void k_csr(
    const int* __restrict__ gcnt, const int* __restrict__ gbin,
    int* __restrict__ cnt, int* __restrict__ adj) {
    int i = blockIdx.x;
    int xcd = i & 7, k = i >> 3;              // blockIdx%8 ~ XCD (round-robin dispatch heuristic)
    int bucket = (k % (NBUK / 8)) * 8 + xcd;  // interleave heavy (dest<100K) buckets across XCDs
    int rep = k / (NBUK / 8);                 // [0, CSR_REP)
    int n = gcnt[bucket];
    const int* bb = gbin + (size_t)bucket * BINCAP * 2;
    const int stride = CSR_REP * 256;
    int idx = rep * 256 + threadIdx.x;
    for (; idx + 3 * stride < n; idx += 4 * stride) {   // 4 independent atomic round-trips in flight
        int2 e0 = *(const int2*)(bb + (size_t)(idx)*2);
        int2 e1 = *(const int2*)(bb + (size_t)(idx + stride) * 2);
        int2 e2 = *(const int2*)(bb + (size_t)(idx + 2 * stride) * 2);
        int2 e3 = *(const int2*)(bb + (size_t)(idx + 3 * stride) * 2);
        int s0 = atomicAdd(&cnt[e0.x], 1);
        int s1 = atomicAdd(&cnt[e1.x], 1);
        int s2 = atomicAdd(&cnt[e2.x], 1);
        int s3 = atomicAdd(&cnt[e3.x], 1);
        adj[(size_t)e0.x * CAP + s0] = e0.y;
        adj[(size_t)e1.x * CAP + s1] = e1.y;
        adj[(size_t)e2.x * CAP + s2] = e2.y;
        adj[(size_t)e3.x * CAP + s3] = e3.y;
    }
    for (; idx < n; idx += stride) {
        int2 e = *(const int2*)(bb + (size_t)idx * 2);
        int s = atomicAdd(&cnt[e.x], 1);
        adj[(size_t)e.x * CAP + s] = e.y;
    }
}

// ---------------- FUSED: x0 = feat@W + b + emb; h1' = dis*(x0@c1W) ----------------
// v3: ALL global loads issued then PINNED above compute via sched_barrier(0) — the compiler
// cannot re-sink them (v2 lesson: source order alone is ignored; VGPR fell to 36 and every
// load serialized). Forces ~56 loads in flight/wave; launch_bounds(256,2) gives the VGPRs.
__global__ __launch_bounds__(256, 2) void k_xform_c1(
    const float* __restrict__ user_feat, const float* __restrict__ prod_feat,
    const short* __restrict__ wts,
    const float* __restrict__ b_uf, const float* __restrict__ b_pf,
    const float* __restrict__ user_emb, const float* __restrict__ prod_emb,
    const int* __restrict__ cnt, unsigned short* __restrict__ h) {
    __shared__ unsigned short lds[4][16 * LDST];
    int tid = threadIdx.x;
    int wave = tid >> 6;
    int tile = blockIdx.x * 4 + wave;
    if (tile >= NT_ALL) return;              // no barrier in kernel -> early exit safe
    int lane = tid & 63, ln = lane & 15, quad = lane >> 4;

    // per-wave operand selection (uniform within wave -> no divergence)
    const float* feat; const short* WT; const float* b; const float* emb;
    int node_off, mtile;
    if (tile < NT_U) {
        feat = user_feat; WT = wts;        b = b_uf; emb = user_emb; node_off = 0;         mtile = tile;
    } else {
        feat = prod_feat; WT = wts + 8192; b = b_pf; emb = prod_emb; node_off = NUM_USERS; mtile = tile - NT_U;
    }
    const short* c1T = wts + 16384;
    int mbase = mtile * 16;

    // ---- issue ALL global loads (HBM feat first, then L2-resident weights/emb/cnt) ----
    const float* arow = feat + (size_t)(mbase + ln) * FDIM + quad * 8;
    float4 fl[4], fh[4];
#pragma unroll
    for (int kk = 0; kk < 4; ++kk) {
        fl[kk] = *(const float4*)(arow + kk * 32);
        fh[kk] = *(const float4*)(arow + kk * 32 + 4);
    }
    float ev[4][4];                           // [r][t]
#pragma unroll
    for (int r = 0; r < 4; ++r)
#pragma unroll
        for (int t = 0; t < 4; ++t)
            ev[r][t] = emb[(size_t)(mbase + quad * 4 + r) * EDIM + t * 16 + ln];
    short8 Bx[4][4];
#pragma unroll
    for (int t = 0; t < 4; ++t)
#pragma unroll
        for (int kk = 0; kk < 4; ++kk)
            Bx[t][kk] = *(const short8*)(WT + ((t * 16 + ln) * 128 + kk * 32 + quad * 8));
    short8 Bc[4][2];
#pragma unroll
    for (int t = 0; t < 4; ++t)
#pragma unroll
        for (int kk = 0; kk < 2; ++kk)
            Bc[t][kk] = *(const short8*)(c1T + ((t * 16 + ln) * 64 + kk * 32 + quad * 8));
    float bv[4];
#pragma unroll
    for (int t = 0; t < 4; ++t) bv[t] = b[t * 16 + ln];
    int cdv[4];
#pragma unroll
    for (int r = 0; r < 4; ++r) cdv[r] = cnt[node_off + mbase + quad * 4 + r];

    __builtin_amdgcn_sched_barrier(0);        // loads stay above; compute stays below

    // ---- GEMM1: x0 = feat @ W ----
    f32x4 acc[4] = {{0.f,0.f,0.f,0.f},{0.f,0.f,0.f,0.f},{0.f,0.f,0.f,0.f},{0.f,0.f,0.f,0.f}};
#pragma unroll
    for (int kk = 0; kk < 4; ++kk) {
        short8 Af;
        Af[0] = f2bf(fl[kk].x); Af[1] = f2bf(fl[kk].y); Af[2] = f2bf(fl[kk].z); Af[3] = f2bf(fl[kk].w);
        Af[4] = f2bf(fh[kk].x); Af[5] = f2bf(fh[kk].y); Af[6] = f2bf(fh[kk].z); Af[7] = f2bf(fh[kk].w);
#pragma unroll
        for (int t = 0; t < 4; ++t)
            acc[t] = __builtin_amdgcn_mfma_f32_16x16x32_bf16(Af, Bx[t][kk], acc[t], 0, 0, 0);
    }
    // x0 epilogue -> LDS tile (bf16, same quantization the old memory round-trip applied)
#pragma unroll
    for (int r = 0; r < 4; ++r)
#pragma unroll
        for (int t = 0; t < 4; ++t) {
            float v = acc[t][r] + bv[t] + ev[r][t];
            lds[wave][(quad * 4 + r) * LDST + t * 16 + ln] = (unsigned short)f2bf(v);
        }
    // intra-wave LDS dependency only: lgkmcnt ordering suffices, no barrier
    // ---- GEMM2: h1' = dis * (x0 @ c1W) ----
    f32x4 acch[4] = {{0.f,0.f,0.f,0.f},{0.f,0.f,0.f,0.f},{0.f,0.f,0.f,0.f},{0.f,0.f,0.f,0.f}};
#pragma unroll
    for (int kk = 0; kk < 2; ++kk) {
        short8 Af = *(const short8*)(&lds[wave][ln * LDST + kk * 32 + quad * 8]);
#pragma unroll
        for (int t = 0; t < 4; ++t)
            acch[t] = __builtin_amdgcn_mfma_f32_16x16x32_bf16(Af, Bc[t][kk], acch[t], 0, 0, 0);
    }
    float disv[4];
#pragma unroll
    for (int r = 0; r < 4; ++r) disv[r] = disf(cdv[r]);
#pragma unroll
    for (int r = 0; r < 4; ++r) {
        int node = mbase + quad * 4 + r;
#pragma unroll
        for (int t = 0; t < 4; ++t)
            h[(size_t)(node_off + node) * EDIM + t * 16 + ln] =
                (unsigned short)f2bf(disv[r] * acch[t][r]);
    }
}

// ---------------- FUSED: x1 = relu(dis*(h1'[d]+Σ h1'[src]) + b1); h2' = dis*(x1@c2W) ----------------
__global__ __launch_bounds__(256) void k_gather_c2(
    const int* __restrict__ adj, const int* __restrict__ cnt,
    const unsigned short* __restrict__ h,
    const float* __restrict__ b1, const short* __restrict__ c2T,
    unsigned short* __restrict__ hout) {
    __shared__ unsigned short lds[4][16 * LDST];
    int tid = threadIdx.x;
    int wave = tid >> 6;
    int tile = blockIdx.x * 4 + wave;
    if (tile >= N_NODES / 16) return;        // no barrier in kernel -> early exit safe
    int lane = tid & 63, ln = lane & 15, quad = lane >> 4;
    const unsigned int* hp = (const unsigned int*)h;    // bf16x2 view, row stride 32

    short8 Bc[4][2];
#pragma unroll
    for (int t = 0; t < 4; ++t)
#pragma unroll
        for (int kk = 0; kk < 2; ++kk)
            Bc[t][kk] = *(const short8*)(c2T + ((t * 16 + ln) * 64 + kk * 32 + quad * 8));

    int mbase = tile * 16;
    float2 bb0 = ((const float2*)b1)[ln];        // feats 2ln, 2ln+1
    float2 bb1 = ((const float2*)b1)[16 + ln];   // feats 32+2ln, 32+2ln+1

#pragma unroll 1
    for (int it = 0; it < 4; ++it) {
        int d = mbase + it * 4 + quad;
        const unsigned int* hrow = hp + (size_t)d * 32;
        unsigned int s0 = hrow[ln], s1 = hrow[16 + ln];          // self-loop term
        float a0 = bf2f((unsigned short)s0);
        float a1 = bf2f((unsigned short)(s0 >> 16));
        float a2 = bf2f((unsigned short)s1);
        float a3 = bf2f((unsigned short)(s1 >> 16));
        int cd = cnt[d];
        const int* ap = adj + (size_t)d * CAP;
        int i = 0;
        for (; i + 1 < cd; i += 2) {                             // 4 gathers in flight/lane
            int r0 = ap[i], r1 = ap[i + 1];
            unsigned int p00 = hp[(size_t)r0 * 32 + ln];
            unsigned int p01 = hp[(size_t)r0 * 32 + 16 + ln];
            unsigned int p10 = hp[(size_t)r1 * 32 + ln];
            unsigned int p11 = hp[(size_t)r1 * 32 + 16 + ln];
            a0 += bf2f((unsigned short)p00) + bf2f((unsigned short)p10);
            a1 += bf2f((unsigned short)(p00 >> 16)) + bf2f((unsigned short)(p10 >> 16));
            a2 += bf2f((unsigned short)p01) + bf2f((unsigned short)p11);
            a3 += bf2f((unsigned short)(p01 >> 16)) + bf2f((unsigned short)(p11 >> 16));
        }
        if (i < cd) {
            int r0 = ap[i];
            unsigned int p00 = hp[(size_t)r0 * 32 + ln];
            unsigned int p01 = hp[(size_t)r0 * 32 + 16 + ln];
            a0 += bf2f((unsigned short)p00);
            a1 += bf2f((unsigned short)(p00 >> 16));
            a2 += bf2f((unsigned short)p01);
            a3 += bf2f((unsigned short)(p01 >> 16));
        }
        float dv = disf(cd);
        float v0 = fmaxf(fmaf(dv, a0, bb0.x), 0.f);
        float v1 = fmaxf(fmaf(dv, a1, bb0.y), 0.f);
        float v2 = fmaxf(fmaf(dv, a2, bb1.x), 0.f);
        float v3 = fmaxf(fmaf(dv, a3, bb1.y), 0.f);
        unsigned int* lrow = (unsigned int*)&lds[wave][(it * 4 + quad) * LDST];
        lrow[ln] = ((unsigned int)(unsigned short)f2bf(v1) << 16)
                 | (unsigned int)(unsigned short)f2bf(v0);
        lrow[16 + ln] = ((unsigned int)(unsigned short)f2bf(v3) << 16)
                      | (unsigned int)(unsigned short)f2bf(v2);
    }
    // intra-wave LDS dependency only: no barrier needed
    // h2' = dis * (x1 @ c2W)
    f32x4 acc[4] = {{0.f,0.f,0.f,0.f},{0.f,0.f,0.f,0.f},{0.f,0.f,0.f,0.f},{0.f,0.f,0.f,0.f}};
#pragma unroll
    for (int kk = 0; kk < 2; ++kk) {
        short8 Af = *(const short8*)(&lds[wave][ln * LDST + kk * 32 + quad * 8]);
#pragma unroll
        for (int t = 0; t < 4; ++t)
            acc[t] = __builtin_amdgcn_mfma_f32_16x16x32_bf16(Af, Bc[t][kk], acc[t], 0, 0, 0);
    }
    float disv[4];
#pragma unroll
    for (int r = 0; r < 4; ++r) disv[r] = disf(cnt[mbase + quad * 4 + r]);
#pragma unroll
    for (int r = 0; r < 4; ++r) {
        int node = mbase + quad * 4 + r;
#pragma unroll
        for (int t = 0; t < 4; ++t)
            hout[(size_t)node * EDIM + t * 16 + ln] = (unsigned short)f2bf(disv[r] * acc[t][r]);
    }
}

// ---------------- gather + finish (conv2 output): x[d] = dis[d]*(h'[d]+Σ h'[src]) + b ----------------
__global__ __launch_bounds__(256) void k_gather(
    const int* __restrict__ adj, const int* __restrict__ cnt,
    const unsigned short* __restrict__ h,
    const float* __restrict__ b, unsigned short* __restrict__ xout, int relu) {
    int d = blockIdx.x * 4 + (threadIdx.x >> 6);
    if (d >= N_NODES) return;
    int l = threadIdx.x & 63;
    int half = l >> 5, c2 = l & 31;              // feature pair c2 -> feats {2c2, 2c2+1}
    const unsigned int* hp = (const unsigned int*)h;   // bf16x2 view, row stride 32

    float ax = 0.f, ay = 0.f;
    if (half == 0) {                              // self-loop term, counted once
        unsigned int pr = hp[(size_t)d * 32 + c2];
        ax = bf2f((unsigned short)pr);
        ay = bf2f((unsigned short)(pr >> 16));
    }
    int c = cnt[d];
    const int* ap = adj + (size_t)d * CAP;
    int i = 0;
    for (; i + 3 < c; i += 4) {
        int s0 = ap[i + half];
        int s1 = ap[i + 2 + half];
        unsigned int p0 = hp[(size_t)s0 * 32 + c2];
        unsigned int p1 = hp[(size_t)s1 * 32 + c2];
        ax += bf2f((unsigned short)p0) + bf2f((unsigned short)p1);
        ay += bf2f((unsigned short)(p0 >> 16)) + bf2f((unsigned short)(p1 >> 16));
    }
    if (i + half < c) {
        unsigned int p0 = hp[(size_t)ap[i + half] * 32 + c2];
        ax += bf2f((unsigned short)p0);
        ay += bf2f((unsigned short)(p0 >> 16));
    }
    if (i + 2 + half < c) {
        unsigned int p0 = hp[(size_t)ap[i + 2 + half] * 32 + c2];
        ax += bf2f((unsigned short)p0);
        ay += bf2f((unsigned short)(p0 >> 16));
    }
    ax += __shfl_xor(ax, 32, 64);                 // combine the two halves
    ay += __shfl_xor(ay, 32, 64);
    float dv = disf(c);
    float2 bb = ((const float2*)b)[c2];
    float v0 = fmaf(dv, ax, bb.x);
    float v1 = fmaf(dv, ay, bb.y);
    if (relu) { v0 = fmaxf(v0, 0.f); v1 = fmaxf(v1, 0.f); }
    if (half == 0) {
        unsigned int pk = ((unsigned int)(unsigned short)f2bf(v1) << 16)
                        | (unsigned int)(unsigned short)f2bf(v0);
        ((unsigned int*)xout)[(size_t)d * 32 + c2] = pk;
    }
}

// ---------------- edge predictor via bf16 MFMA, ei prefetch + hoisted A loads ----------------
__global__ __launch_bounds__(256) void k_pred_mfma(
    const int* __restrict__ ei, const unsigned short* __restrict__ x,
    const short* __restrict__ W1T, const float* __restrict__ b1,
    const float* __restrict__ W2, const float* __restrict__ b2,
    float* __restrict__ preds) {
    int tid = threadIdx.x;
    int wave = tid >> 6, lane = tid & 63;
    int ln = lane & 15, quad = lane >> 4;

    short8 Bf[4][4];
#pragma unroll
    for (int t = 0; t < 4; ++t)
#pragma unroll
        for (int kk = 0; kk < 4; ++kk)
            Bf[t][kk] = *(const short8*)(W1T + ((t * 16 + ln) * 128 + kk * 32 + quad * 8));

    float b1v[4], W2v[4];
#pragma unroll
    for (int t = 0; t < 4; ++t) {
        b1v[t] = b1[t * 16 + ln];
        W2v[t] = W2[t * 16 + ln];
    }
    float b2s = b2[0];

    const int n_tiles = N_EDGES / 16;
    int gw = blockIdx.x * 4 + wave;
    int nwaves = gridDim.x * 4;

    int cu = 0, cp = 0;
    if (gw < n_tiles) {
        cu = ei[gw * 16 + ln];
        cp = ei[N_EDGES + gw * 16 + ln] + NUM_USERS;
    }
    for (int tile = gw; tile < n_tiles; tile += nwaves) {
        int u = cu, p = cp;
        int nt = tile + nwaves;
        if (nt < n_tiles) {                       // prefetch next tile's indices
            cu = ei[nt * 16 + ln];
            cp = ei[N_EDGES + nt * 16 + ln] + NUM_USERS;
        }
        short8 Af[4];                             // all 4 A loads in flight
        Af[0] = *(const short8*)(x + (size_t)u * EDIM + quad * 8);
        Af[1] = *(const short8*)(x + (size_t)u * EDIM + 32 + quad * 8);
        Af[2] = *(const short8*)(x + (size_t)p * EDIM + quad * 8);
        Af[3] = *(const short8*)(x + (size_t)p * EDIM + 32 + quad * 8);

        f32x4 acc[4] = {{0.f,0.f,0.f,0.f},{0.f,0.f,0.f,0.f},{0.f,0.f,0.f,0.f},{0.f,0.f,0.f,0.f}};
#pragma unroll
        for (int kk = 0; kk < 4; ++kk)
#pragma unroll
            for (int t = 0; t < 4; ++t)
                acc[t] = __builtin_amdgcn_mfma_f32_16x16x32_bf16(Af[kk], Bf[t][kk], acc[t], 0, 0, 0);

        float out[4];
#pragma unroll
        for (int r = 0; r < 4; ++r) {
            float part = 0.f;
#pragma unroll
            for (int t = 0; t < 4; ++t) {
                float hv = fmaxf(acc[t][r] + b1v[t], 0.f);
                part = fmaf(hv, W2v[t], part);
            }
            part += __shfl_xor(part, 1, 64);
            part += __shfl_xor(part, 2, 64);
            part += __shfl_xor(part, 4, 64);
            part += __shfl_xor(part, 8, 64);
            out[r] = part;
        }
        if (ln == 0) {
            int ebase = tile * 16;
#pragma unroll
            for (int r = 0; r < 4; ++r) {
                float logit = out[r] + b2s;
                preds[ebase + quad * 4 + r] = 5.f / (1.f + expf(-logit));
            }
        }
    }
}

extern "C" void kernel_launch(void* const* d_in, const int* in_sizes, int n_in,
                              void* d_out, int out_size, void* d_ws, size_t ws_size,
                              hipStream_t stream) {
    const int*   ei        = (const int*)d_in[0];
    const float* user_feat = (const float*)d_in[1];
    const float* prod_feat = (const float*)d_in[2];
    const float* user_emb  = (const float*)d_in[3];
    const float* prod_emb  = (const float*)d_in[4];
    const float* W_uf      = (const float*)d_in[5];
    const float* b_uf      = (const float*)d_in[6];
    const float* W_pf      = (const float*)d_in[7];
    const float* b_pf      = (const float*)d_in[8];
    const float* conv1_W   = (const float*)d_in[9];
    const float* conv1_b   = (const float*)d_in[10];
    const float* conv2_W   = (const float*)d_in[11];
    const float* conv2_b   = (const float*)d_in[12];
    const float* pred_W1   = (const float*)d_in[13];
    const float* pred_b1   = (const float*)d_in[14];
    const float* pred_W2   = (const float*)d_in[15];
    const float* pred_b2   = (const float*)d_in[16];

    // workspace layout (4-byte units)
    int* ws_i = (int*)d_ws;
    int*   cnt  = ws_i;                            // 300032 + NBUK bucket counters right after
    int*   gcnt = ws_i + 300032;                   // 80 ints (zeroed with cnt)
    int*   adj  = ws_i + 600064;                   // 300032*40 = 12,001,280
    unsigned short* xbuf = (unsigned short*)(ws_i + 12601344);  // 38.4MB; gbin overlays (dead until gather_c2)
    int*   gbin = ws_i + 12601344;                 // 80*49152 int2 entries = 31.5MB
    unsigned short* hbuf = (unsigned short*)(ws_i + 22201344);  // 38.4MB
    short* wts = (short*)(ws_i + 31801344);        // 32768 bf16
    float* preds = (float*)d_out;

    // setup (zero cnt+gcnt + weight prep), then two-phase binned CSR build
    k_setup<<<ZERO_BLK + 128, 256, 0, stream>>>(cnt, W_uf, W_pf, conv1_W, conv2_W, pred_W1, wts);
    k_bin<<<(N_EDGES / 4 + 255) / 256, 256, 0, stream>>>(ei, gcnt, gbin);
    k_csr<<<NBUK * CSR_REP, 256, 0, stream>>>(gcnt, gbin, cnt, adj);

    // fused node-transform + conv1 GEMM (users+products, one dispatch) -> hbuf = h1'
    k_xform_c1<<<(NT_ALL + 3) / 4, 256, 0, stream>>>(user_feat, prod_feat, wts,
                                                     b_uf, b_pf, user_emb, prod_emb,
                                                     cnt, hbuf);

    // fused conv1-gather + conv2 GEMM -> xbuf = h2' (gbin dead from here); x1 never hits memory
    k_gather_c2<<<(18750 + 3) / 4, 256, 0, stream>>>(adj, cnt, hbuf, conv1_b,
                                                     wts + 20480, xbuf);
    // conv2 gather -> hbuf = x2 (final node embeddings)
    k_gather<<<N_NODES / 4, 256, 0, stream>>>(adj, cnt, xbuf, conv2_b, hbuf, 0);

    // predictor
    k_pred_mfma<<<2048, 256, 0, stream>>>(ei, hbuf, wts + 24576, pred_b1, pred_W2, pred_b2, preds);
}

// Round 7
// 670.637 us; speedup vs baseline: 1.0181x; 1.0142x over previous
//
#include <hip/hip_runtime.h>
#include <math.h>

#define NUM_USERS 200000
#define NUM_PRODUCTS 100000
#define N_NODES 300000
#define N_EDGES 1000000
#define EDIM 64
#define FDIM 128
#define CAP 40            // fixed adjacency capacity/node; max degree ~27 (Poisson(10) tail)
#define LDST 72           // LDS tile row stride in u16 (144 B: 16B-aligned, breaks pow2 banks)
#define NT_U 12500        // user tiles
#define NT_P 6250         // product tiles
#define NT_ALL 18750      // total node tiles
#define ZERO_BLK 1173     // 1173*256 = 300288 >= 300032 cnt + 80 bucket counters
#define NBUK 80           // CSR bins: dest in [0,200000), 2500 nodes/bucket (400KB adj region)
#define BNODES 2500
#define BINCAP 49152      // max bucket load ~37.5K entries; 80*49152*8B = 31.5MB (overlays xbuf)
#define CSR_REP 4         // blocks per bucket in k_csr (XCD-affine)
#define XC1_BLOCKS 1024   // persistent-wave grid for k_xform_c1
#define XC1_WAVES (XC1_BLOCKS * 4)   // 4096
#define XC1_UW 2731       // user waves (~ 4096 * 12500/18750); product waves = 1365

typedef __attribute__((ext_vector_type(8))) short short8;   // 8 bf16 in 4 VGPRs
typedef __attribute__((ext_vector_type(4))) float f32x4;    // MFMA accumulator

// fp32 -> bf16 round-to-nearest-even
static __device__ inline short f2bf(float f) {
    unsigned int u = __float_as_uint(f);
    unsigned int r = (u + 0x7FFFu + ((u >> 16) & 1u)) >> 16;
    return (short)r;
}
static __device__ inline float bf2f(unsigned short s) {
    return __uint_as_float(((unsigned int)s) << 16);
}
// deg^-1/2 with self-loop; same v_rsq_f32 the old k_dis used -> bit-identical numerics
static __device__ inline float disf(int c) {
    return rsqrtf(1.0f + (float)c);
}

// ---------------- setup: zero cnt + bucket counters + weight prep ----------------
// wts layout (shorts): WufT@0(8192) WpfT@8192(8192) c1T@16384(4096) c2T@20480(4096) W1T@24576(8192)
__global__ void k_setup(int* __restrict__ cnt,
                        const float* __restrict__ W_uf, const float* __restrict__ W_pf,
                        const float* __restrict__ c1, const float* __restrict__ c2,
                        const float* __restrict__ W1, short* __restrict__ wts) {
    int b = blockIdx.x;
    if (b < ZERO_BLK) {
        int i = b * 256 + threadIdx.x;
        if (i < 300032 + NBUK) cnt[i] = 0;   // cnt + gbin_cnt (contiguous)
        return;
    }
    int gid = (b - ZERO_BLK) * 256 + threadIdx.x;
    if (gid >= 32768) return;
    if (gid < 8192) {
        int n = gid >> 7, k = gid & 127;
        wts[gid] = f2bf(W_uf[k * 64 + n]);
    } else if (gid < 16384) {
        int i = gid - 8192; int n = i >> 7, k = i & 127;
        wts[gid] = f2bf(W_pf[k * 64 + n]);
    } else if (gid < 20480) {
        int i = gid - 16384; int n = i >> 6, k = i & 63;
        wts[gid] = f2bf(c1[k * 64 + n]);
    } else if (gid < 24576) {
        int i = gid - 20480; int n = i >> 6, k = i & 63;
        wts[gid] = f2bf(c2[k * 64 + n]);
    } else {
        int i = gid - 24576; int n = i >> 7, k = i & 127;
        wts[gid] = f2bf(W1[k * 64 + n]);
    }
}

// ---------------- CSR phase 1: LDS-binned edge scatter into per-bucket streams ----------------
__global__ __launch_bounds__(256) void k_bin(
    const int* __restrict__ ei, int* __restrict__ gcnt, int* __restrict__ gbin) {
    __shared__ int lcnt[NBUK];
    __shared__ int lbase[NBUK];
    int tid = threadIdx.x;
    if (tid < NBUK) lcnt[tid] = 0;
    __syncthreads();
    int e0 = (blockIdx.x * 256 + tid) * 4;
    bool act = e0 < N_EDGES;
    int d[8], s[8], rk[8], bk[8];
    if (act) {
        int4 uu = *(const int4*)(ei + e0);            // user ids
        int4 pp = *(const int4*)(ei + N_EDGES + e0);  // raw (un-offset) product ids — reference quirk
        d[0] = pp.x; s[0] = uu.x;  d[1] = uu.x; s[1] = pp.x;
        d[2] = pp.y; s[2] = uu.y;  d[3] = uu.y; s[3] = pp.y;
        d[4] = pp.z; s[4] = uu.z;  d[5] = uu.z; s[5] = pp.z;
        d[6] = pp.w; s[6] = uu.w;  d[7] = uu.w; s[7] = pp.w;
#pragma unroll
        for (int j = 0; j < 8; ++j) {
            bk[j] = d[j] / BNODES;                    // dest < 200000 always
            rk[j] = atomicAdd(&lcnt[bk[j]], 1);
        }
    }
    __syncthreads();
    if (tid < NBUK) lbase[tid] = atomicAdd(&gcnt[tid], lcnt[tid]);
    __syncthreads();
    if (act) {
#pragma unroll
        for (int j = 0; j < 8; ++j) {
            int pos = lbase[bk[j]] + rk[j];
            if (pos < BINCAP)                         // safety guard (expected max ~38K << 49152)
                *(int2*)(gbin + ((size_t)bk[j] * BINCAP + pos) * 2) = make_int2(d[j], s[j]);
        }
    }
}

// ---------------- CSR phase 2: per-bucket slot assignment, XCD-affine for L2 write merging ----------------
__global__ __launch_bounds__(256) void k_csr(
    const int* __restrict__ gcnt, const int* __restrict__ gbin,
    int* __restrict__ cnt, int* __restrict__ adj) {
    int i = blockIdx.x;
    int xcd = i & 7, k = i >> 3;              // blockIdx%8 ~ XCD (round-robin dispatch heuristic)
    int bucket = (k % (NBUK / 8)) * 8 + xcd;  // interleave heavy (dest<100K) buckets across XCDs
    int rep = k / (NBUK / 8);                 // [0, CSR_REP)
    int n = gcnt[bucket];
    const int* bb = gbin + (size_t)bucket * BINCAP * 2;
    const int stride = CSR_REP * 256;
    int idx = rep * 256 + threadIdx.x;
    for (; idx + 3 * stride < n; idx += 4 * stride) {   // 4 independent atomic round-trips in flight
        int2 e0 = *(const int2*)(bb + (size_t)(idx)*2);
        int2 e1 = *(const int2*)(bb + (size_t)(idx + stride) * 2);
        int2 e2 = *(const int2*)(bb + (size_t)(idx + 2 * stride) * 2);
        int2 e3 = *(const int2*)(bb + (size_t)(idx + 3 * stride) * 2);
        int s0 = atomicAdd(&cnt[e0.x], 1);
        int s1 = atomicAdd(&cnt[e1.x], 1);
        int s2 = atomicAdd(&cnt[e2.x], 1);
        int s3 = atomicAdd(&cnt[e3.x], 1);
        adj[(size_t)e0.x * CAP + s0] = e0.y;
        adj[(size_t)e1.x * CAP + s1] = e1.y;
        adj[(size_t)e2.x * CAP + s2] = e2.y;
        adj[(size_t)e3.x * CAP + s3] = e3.y;
    }
    for (; idx < n; idx += stride) {
        int2 e = *(const int2*)(bb + (size_t)idx * 2);
        int s = atomicAdd(&cnt[e.x], 1);
        adj[(size_t)e.x * CAP + s] = e.y;
    }
}

// ---------------- FUSED: x0 = feat@W + b + emb; h1' = dis*(x0@c1W) ----------------
// v4: persistent waves + 2-stage software pipeline. Straight-line hoisting failed twice
// (compiler re-sinks loads, VGPR 36/64); cross-iteration loads are the pattern the
// scheduler DOES keep in flight. Weights loop-invariant per wave (user/product wave split).
#define XC1_LOAD(S, MT) do {                                                         \
    int mb_ = (MT) * 16;                                                             \
    const float* ar_ = feat + (size_t)(mb_ + ln) * FDIM + quad * 8;                  \
    _Pragma("unroll")                                                                \
    for (int kk_ = 0; kk_ < 4; ++kk_) {                                              \
        fl##S[kk_] = *(const float4*)(ar_ + kk_ * 32);                               \
        fh##S[kk_] = *(const float4*)(ar_ + kk_ * 32 + 4);                           \
    }                                                                                \
    _Pragma("unroll")                                                                \
    for (int r_ = 0; r_ < 4; ++r_)                                                   \
        _Pragma("unroll")                                                            \
        for (int t_ = 0; t_ < 4; ++t_)                                               \
            ev##S[r_][t_] = emb[(size_t)(mb_ + quad * 4 + r_) * EDIM + t_ * 16 + ln];\
    _Pragma("unroll")                                                                \
    for (int r_ = 0; r_ < 4; ++r_)                                                   \
        cd##S[r_] = cnt[node_off + mb_ + quad * 4 + r_];                             \
} while (0)

#define XC1_COMPUTE(S, MT) do {                                                      \
    int mb_ = (MT) * 16;                                                             \
    f32x4 acc_[4] = {{0.f,0.f,0.f,0.f},{0.f,0.f,0.f,0.f},{0.f,0.f,0.f,0.f},{0.f,0.f,0.f,0.f}}; \
    _Pragma("unroll")                                                                \
    for (int kk_ = 0; kk_ < 4; ++kk_) {                                              \
        short8 Af_;                                                                  \
        Af_[0] = f2bf(fl##S[kk_].x); Af_[1] = f2bf(fl##S[kk_].y);                    \
        Af_[2] = f2bf(fl##S[kk_].z); Af_[3] = f2bf(fl##S[kk_].w);                    \
        Af_[4] = f2bf(fh##S[kk_].x); Af_[5] = f2bf(fh##S[kk_].y);                    \
        Af_[6] = f2bf(fh##S[kk_].z); Af_[7] = f2bf(fh##S[kk_].w);                    \
        _Pragma("unroll")                                                            \
        for (int t_ = 0; t_ < 4; ++t_)                                               \
            acc_[t_] = __builtin_amdgcn_mfma_f32_16x16x32_bf16(Af_, Bx[t_][kk_], acc_[t_], 0, 0, 0); \
    }                                                                                \
    _Pragma("unroll")                                                                \
    for (int r_ = 0; r_ < 4; ++r_)                                                   \
        _Pragma("unroll")                                                            \
        for (int t_ = 0; t_ < 4; ++t_) {                                             \
            float v_ = acc_[t_][r_] + bv[t_] + ev##S[r_][t_];                        \
            lds[wave][(quad * 4 + r_) * LDST + t_ * 16 + ln] = (unsigned short)f2bf(v_); \
        }                                                                            \
    f32x4 acch_[4] = {{0.f,0.f,0.f,0.f},{0.f,0.f,0.f,0.f},{0.f,0.f,0.f,0.f},{0.f,0.f,0.f,0.f}}; \
    _Pragma("unroll")                                                                \
    for (int kk_ = 0; kk_ < 2; ++kk_) {                                              \
        short8 Af_ = *(const short8*)(&lds[wave][ln * LDST + kk_ * 32 + quad * 8]);  \
        _Pragma("unroll")                                                            \
        for (int t_ = 0; t_ < 4; ++t_)                                               \
            acch_[t_] = __builtin_amdgcn_mfma_f32_16x16x32_bf16(Af_, Bc[t_][kk_], acch_[t_], 0, 0, 0); \
    }                                                                                \
    _Pragma("unroll")                                                                \
    for (int r_ = 0; r_ < 4; ++r_) {                                                 \
        float dv_ = disf(cd##S[r_]);                                                 \
        int node_ = mb_ + quad * 4 + r_;                                             \
        _Pragma("unroll")                                                            \
        for (int t_ = 0; t_ < 4; ++t_)                                               \
            h[(size_t)(node_off + node_) * EDIM + t_ * 16 + ln] =                    \
                (unsigned short)f2bf(dv_ * acch_[t_][r_]);                           \
    }                                                                                \
} while (0)

__global__ __launch_bounds__(256, 2) void k_xform_c1(
    const float* __restrict__ user_feat, const float* __restrict__ prod_feat,
    const short* __restrict__ wts,
    const float* __restrict__ b_uf, const float* __restrict__ b_pf,
    const float* __restrict__ user_emb, const float* __restrict__ prod_emb,
    const int* __restrict__ cnt, unsigned short* __restrict__ h) {
    __shared__ unsigned short lds[4][16 * LDST];
    int tid = threadIdx.x;
    int wave = tid >> 6;
    int lane = tid & 63, ln = lane & 15, quad = lane >> 4;
    int gw = blockIdx.x * 4 + wave;

    // wave-static operand selection: user waves [0,XC1_UW), product waves [XC1_UW,4096)
    const float* feat; const short* WT; const float* b; const float* emb;
    int node_off, t0, tcnt, tstride;
    if (gw < XC1_UW) {
        feat = user_feat; WT = wts;        b = b_uf; emb = user_emb;
        node_off = 0;         t0 = gw;          tcnt = NT_U; tstride = XC1_UW;
    } else {
        feat = prod_feat; WT = wts + 8192; b = b_pf; emb = prod_emb;
        node_off = NUM_USERS; t0 = gw - XC1_UW; tcnt = NT_P; tstride = XC1_WAVES - XC1_UW;
    }
    if (t0 >= tcnt) return;
    const short* c1T = wts + 16384;

    // loop-invariant weights (resident all iterations)
    short8 Bx[4][4];
#pragma unroll
    for (int t = 0; t < 4; ++t)
#pragma unroll
        for (int kk = 0; kk < 4; ++kk)
            Bx[t][kk] = *(const short8*)(WT + ((t * 16 + ln) * 128 + kk * 32 + quad * 8));
    short8 Bc[4][2];
#pragma unroll
    for (int t = 0; t < 4; ++t)
#pragma unroll
        for (int kk = 0; kk < 2; ++kk)
            Bc[t][kk] = *(const short8*)(c1T + ((t * 16 + ln) * 64 + kk * 32 + quad * 8));
    float bv[4];
#pragma unroll
    for (int t = 0; t < 4; ++t) bv[t] = b[t * 16 + ln];

    // two explicit pipeline stages (A/B named regs — no runtime-indexed buffers)
    float4 flA[4], fhA[4], flB[4], fhB[4];
    float evA[4][4], evB[4][4];
    int cdA[4], cdB[4];

    int t = t0;
    XC1_LOAD(A, t);
    for (;;) {
        int tn = t + tstride;
        bool hasB = tn < tcnt;
        if (hasB) XC1_LOAD(B, tn);       // next tile's loads in flight over current compute
        XC1_COMPUTE(A, t);
        if (!hasB) break;
        t = tn;
        tn = t + tstride;
        bool hasA = tn < tcnt;
        if (hasA) XC1_LOAD(A, tn);
        XC1_COMPUTE(B, t);
        if (!hasA) break;
        t = tn;
    }
}

// ---------------- FUSED: x1 = relu(dis*(h1'[d]+Σ h1'[src]) + b1); h2' = dis*(x1@c2W) ----------------
__global__ __launch_bounds__(256) void k_gather_c2(
    const int* __restrict__ adj, const int* __restrict__ cnt,
    const unsigned short* __restrict__ h,
    const float* __restrict__ b1, const short* __restrict__ c2T,
    unsigned short* __restrict__ hout) {
    __shared__ unsigned short lds[4][16 * LDST];
    int tid = threadIdx.x;
    int wave = tid >> 6;
    int tile = blockIdx.x * 4 + wave;
    if (tile >= N_NODES / 16) return;        // no barrier in kernel -> early exit safe
    int lane = tid & 63, ln = lane & 15, quad = lane >> 4;
    const unsigned int* hp = (const unsigned int*)h;    // bf16x2 view, row stride 32

    short8 Bc[4][2];
#pragma unroll
    for (int t = 0; t < 4; ++t)
#pragma unroll
        for (int kk = 0; kk < 2; ++kk)
            Bc[t][kk] = *(const short8*)(c2T + ((t * 16 + ln) * 64 + kk * 32 + quad * 8));

    int mbase = tile * 16;
    float2 bb0 = ((const float2*)b1)[ln];        // feats 2ln, 2ln+1
    float2 bb1 = ((const float2*)b1)[16 + ln];   // feats 32+2ln, 32+2ln+1

#pragma unroll 1
    for (int it = 0; it < 4; ++it) {
        int d = mbase + it * 4 + quad;
        const unsigned int* hrow = hp + (size_t)d * 32;
        unsigned int s0 = hrow[ln], s1 = hrow[16 + ln];          // self-loop term
        float a0 = bf2f((unsigned short)s0);
        float a1 = bf2f((unsigned short)(s0 >> 16));
        float a2 = bf2f((unsigned short)s1);
        float a3 = bf2f((unsigned short)(s1 >> 16));
        int cd = cnt[d];
        const int* ap = adj + (size_t)d * CAP;
        int i = 0;
        for (; i + 1 < cd; i += 2) {                             // 4 gathers in flight/lane
            int r0 = ap[i], r1 = ap[i + 1];
            unsigned int p00 = hp[(size_t)r0 * 32 + ln];
            unsigned int p01 = hp[(size_t)r0 * 32 + 16 + ln];
            unsigned int p10 = hp[(size_t)r1 * 32 + ln];
            unsigned int p11 = hp[(size_t)r1 * 32 + 16 + ln];
            a0 += bf2f((unsigned short)p00) + bf2f((unsigned short)p10);
            a1 += bf2f((unsigned short)(p00 >> 16)) + bf2f((unsigned short)(p10 >> 16));
            a2 += bf2f((unsigned short)p01) + bf2f((unsigned short)p11);
            a3 += bf2f((unsigned short)(p01 >> 16)) + bf2f((unsigned short)(p11 >> 16));
        }
        if (i < cd) {
            int r0 = ap[i];
            unsigned int p00 = hp[(size_t)r0 * 32 + ln];
            unsigned int p01 = hp[(size_t)r0 * 32 + 16 + ln];
            a0 += bf2f((unsigned short)p00);
            a1 += bf2f((unsigned short)(p00 >> 16));
            a2 += bf2f((unsigned short)p01);
            a3 += bf2f((unsigned short)(p01 >> 16));
        }
        float dv = disf(cd);
        float v0 = fmaxf(fmaf(dv, a0, bb0.x), 0.f);
        float v1 = fmaxf(fmaf(dv, a1, bb0.y), 0.f);
        float v2 = fmaxf(fmaf(dv, a2, bb1.x), 0.f);
        float v3 = fmaxf(fmaf(dv, a3, bb1.y), 0.f);
        unsigned int* lrow = (unsigned int*)&lds[wave][(it * 4 + quad) * LDST];
        lrow[ln] = ((unsigned int)(unsigned short)f2bf(v1) << 16)
                 | (unsigned int)(unsigned short)f2bf(v0);
        lrow[16 + ln] = ((unsigned int)(unsigned short)f2bf(v3) << 16)
                      | (unsigned int)(unsigned short)f2bf(v2);
    }
    // intra-wave LDS dependency only: no barrier needed
    // h2' = dis * (x1 @ c2W)
    f32x4 acc[4] = {{0.f,0.f,0.f,0.f},{0.f,0.f,0.f,0.f},{0.f,0.f,0.f,0.f},{0.f,0.f,0.f,0.f}};
#pragma unroll
    for (int kk = 0; kk < 2; ++kk) {
        short8 Af = *(const short8*)(&lds[wave][ln * LDST + kk * 32 + quad * 8]);
#pragma unroll
        for (int t = 0; t < 4; ++t)
            acc[t] = __builtin_amdgcn_mfma_f32_16x16x32_bf16(Af, Bc[t][kk], acc[t], 0, 0, 0);
    }
    float disv[4];
#pragma unroll
    for (int r = 0; r < 4; ++r) disv[r] = disf(cnt[mbase + quad * 4 + r]);
#pragma unroll
    for (int r = 0; r < 4; ++r) {
        int node = mbase + quad * 4 + r;
#pragma unroll
        for (int t = 0; t < 4; ++t)
            hout[(size_t)node * EDIM + t * 16 + ln] = (unsigned short)f2bf(disv[r] * acc[t][r]);
    }
}

// ---------------- gather + finish (conv2 output): x[d] = dis[d]*(h'[d]+Σ h'[src]) + b ----------------
__global__ __launch_bounds__(256) void k_gather(
    const int* __restrict__ adj, const int* __restrict__ cnt,
    const unsigned short* __restrict__ h,
    const float* __restrict__ b, unsigned short* __restrict__ xout, int relu) {
    int d = blockIdx.x * 4 + (threadIdx.x >> 6);
    if (d >= N_NODES) return;
    int l = threadIdx.x & 63;
    int half = l >> 5, c2 = l & 31;              // feature pair c2 -> feats {2c2, 2c2+1}
    const unsigned int* hp = (const unsigned int*)h;   // bf16x2 view, row stride 32

    float ax = 0.f, ay = 0.f;
    if (half == 0) {                              // self-loop term, counted once
        unsigned int pr = hp[(size_t)d * 32 + c2];
        ax = bf2f((unsigned short)pr);
        ay = bf2f((unsigned short)(pr >> 16));
    }
    int c = cnt[d];
    const int* ap = adj + (size_t)d * CAP;
    int i = 0;
    for (; i + 3 < c; i += 4) {
        int s0 = ap[i + half];
        int s1 = ap[i + 2 + half];
        unsigned int p0 = hp[(size_t)s0 * 32 + c2];
        unsigned int p1 = hp[(size_t)s1 * 32 + c2];
        ax += bf2f((unsigned short)p0) + bf2f((unsigned short)p1);
        ay += bf2f((unsigned short)(p0 >> 16)) + bf2f((unsigned short)(p1 >> 16));
    }
    if (i + half < c) {
        unsigned int p0 = hp[(size_t)ap[i + half] * 32 + c2];
        ax += bf2f((unsigned short)p0);
        ay += bf2f((unsigned short)(p0 >> 16));
    }
    if (i + 2 + half < c) {
        unsigned int p0 = hp[(size_t)ap[i + 2 + half] * 32 + c2];
        ax += bf2f((unsigned short)p0);
        ay += bf2f((unsigned short)(p0 >> 16));
    }
    ax += __shfl_xor(ax, 32, 64);                 // combine the two halves
    ay += __shfl_xor(ay, 32, 64);
    float dv = disf(c);
    float2 bb = ((const float2*)b)[c2];
    float v0 = fmaf(dv, ax, bb.x);
    float v1 = fmaf(dv, ay, bb.y);
    if (relu) { v0 = fmaxf(v0, 0.f); v1 = fmaxf(v1, 0.f); }
    if (half == 0) {
        unsigned int pk = ((unsigned int)(unsigned short)f2bf(v1) << 16)
                        | (unsigned int)(unsigned short)f2bf(v0);
        ((unsigned int*)xout)[(size_t)d * 32 + c2] = pk;
    }
}

// ---------------- edge predictor via bf16 MFMA, ei prefetch + hoisted A loads ----------------
__global__ __launch_bounds__(256) void k_pred_mfma(
    const int* __restrict__ ei, const unsigned short* __restrict__ x,
    const short* __restrict__ W1T, const float* __restrict__ b1,
    const float* __restrict__ W2, const float* __restrict__ b2,
    float* __restrict__ preds) {
    int tid = threadIdx.x;
    int wave = tid >> 6, lane = tid & 63;
    int ln = lane & 15, quad = lane >> 4;

    short8 Bf[4][4];
#pragma unroll
    for (int t = 0; t < 4; ++t)
#pragma unroll
        for (int kk = 0; kk < 4; ++kk)
            Bf[t][kk] = *(const short8*)(W1T + ((t * 16 + ln) * 128 + kk * 32 + quad * 8));

    float b1v[4], W2v[4];
#pragma unroll
    for (int t = 0; t < 4; ++t) {
        b1v[t] = b1[t * 16 + ln];
        W2v[t] = W2[t * 16 + ln];
    }
    float b2s = b2[0];

    const int n_tiles = N_EDGES / 16;
    int gw = blockIdx.x * 4 + wave;
    int nwaves = gridDim.x * 4;

    int cu = 0, cp = 0;
    if (gw < n_tiles) {
        cu = ei[gw * 16 + ln];
        cp = ei[N_EDGES + gw * 16 + ln] + NUM_USERS;
    }
    for (int tile = gw; tile < n_tiles; tile += nwaves) {
        int u = cu, p = cp;
        int nt = tile + nwaves;
        if (nt < n_tiles) {                       // prefetch next tile's indices
            cu = ei[nt * 16 + ln];
            cp = ei[N_EDGES + nt * 16 + ln] + NUM_USERS;
        }
        short8 Af[4];                             // all 4 A loads in flight
        Af[0] = *(const short8*)(x + (size_t)u * EDIM + quad * 8);
        Af[1] = *(const short8*)(x + (size_t)u * EDIM + 32 + quad * 8);
        Af[2] = *(const short8*)(x + (size_t)p * EDIM + quad * 8);
        Af[3] = *(const short8*)(x + (size_t)p * EDIM + 32 + quad * 8);

        f32x4 acc[4] = {{0.f,0.f,0.f,0.f},{0.f,0.f,0.f,0.f},{0.f,0.f,0.f,0.f},{0.f,0.f,0.f,0.f}};
#pragma unroll
        for (int kk = 0; kk < 4; ++kk)
#pragma unroll
            for (int t = 0; t < 4; ++t)
                acc[t] = __builtin_amdgcn_mfma_f32_16x16x32_bf16(Af[kk], Bf[t][kk], acc[t], 0, 0, 0);

        float out[4];
#pragma unroll
        for (int r = 0; r < 4; ++r) {
            float part = 0.f;
#pragma unroll
            for (int t = 0; t < 4; ++t) {
                float hv = fmaxf(acc[t][r] + b1v[t], 0.f);
                part = fmaf(hv, W2v[t], part);
            }
            part += __shfl_xor(part, 1, 64);
            part += __shfl_xor(part, 2, 64);
            part += __shfl_xor(part, 4, 64);
            part += __shfl_xor(part, 8, 64);
            out[r] = part;
        }
        if (ln == 0) {
            int ebase = tile * 16;
#pragma unroll
            for (int r = 0; r < 4; ++r) {
                float logit = out[r] + b2s;
                preds[ebase + quad * 4 + r] = 5.f / (1.f + expf(-logit));
            }
        }
    }
}

extern "C" void kernel_launch(void* const* d_in, const int* in_sizes, int n_in,
                              void* d_out, int out_size, void* d_ws, size_t ws_size,
                              hipStream_t stream) {
    const int*   ei        = (const int*)d_in[0];
    const float* user_feat = (const float*)d_in[1];
    const float* prod_feat = (const float*)d_in[2];
    const float* user_emb  = (const float*)d_in[3];
    const float* prod_emb  = (const float*)d_in[4];
    const float* W_uf      = (const float*)d_in[5];
    const float* b_uf      = (const float*)d_in[6];
    const float* W_pf      = (const float*)d_in[7];
    const float* b_pf      = (const float*)d_in[8];
    const float* conv1_W   = (const float*)d_in[9];
    const float* conv1_b   = (const float*)d_in[10];
    const float* conv2_W   = (const float*)d_in[11];
    const float* conv2_b   = (const float*)d_in[12];
    const float* pred_W1   = (const float*)d_in[13];
    const float* pred_b1   = (const float*)d_in[14];
    const float* pred_W2   = (const float*)d_in[15];
    const float* pred_b2   = (const float*)d_in[16];

    // workspace layout (4-byte units)
    int* ws_i = (int*)d_ws;
    int*   cnt  = ws_i;                            // 300032 + NBUK bucket counters right after
    int*   gcnt = ws_i + 300032;                   // 80 ints (zeroed with cnt)
    int*   adj  = ws_i + 600064;                   // 300032*40 = 12,001,280
    unsigned short* xbuf = (unsigned short*)(ws_i + 12601344);  // 38.4MB; gbin overlays (dead until gather_c2)
    int*   gbin = ws_i + 12601344;                 // 80*49152 int2 entries = 31.5MB
    unsigned short* hbuf = (unsigned short*)(ws_i + 22201344);  // 38.4MB
    short* wts = (short*)(ws_i + 31801344);        // 32768 bf16
    float* preds = (float*)d_out;

    // setup (zero cnt+gcnt + weight prep), then two-phase binned CSR build
    k_setup<<<ZERO_BLK + 128, 256, 0, stream>>>(cnt, W_uf, W_pf, conv1_W, conv2_W, pred_W1, wts);
    k_bin<<<(N_EDGES / 4 + 255) / 256, 256, 0, stream>>>(ei, gcnt, gbin);
    k_csr<<<NBUK * CSR_REP, 256, 0, stream>>>(gcnt, gbin, cnt, adj);

    // fused node-transform + conv1 GEMM (persistent waves, 2-stage pipeline) -> hbuf = h1'
    k_xform_c1<<<XC1_BLOCKS, 256, 0, stream>>>(user_feat, prod_feat, wts,
                                               b_uf, b_pf, user_emb, prod_emb,
                                               cnt, hbuf);

    // fused conv1-gather + conv2 GEMM -> xbuf = h2' (gbin dead from here); x1 never hits memory
    k_gather_c2<<<(18750 + 3) / 4, 256, 0, stream>>>(adj, cnt, hbuf, conv1_b,
                                                     wts + 20480, xbuf);
    // conv2 gather -> hbuf = x2 (final node embeddings)
    k_gather<<<N_NODES / 4, 256, 0, stream>>>(adj, cnt, xbuf, conv2_b, hbuf, 0);

    // predictor
    k_pred_mfma<<<2048, 256, 0, stream>>>(ei, hbuf, wts + 24576, pred_b1, pred_W2, pred_b2, preds);
}

// Round 8
// 582.594 us; speedup vs baseline: 1.1720x; 1.1511x over previous
//
#include <hip/hip_runtime.h>
#include <math.h>

#define NUM_USERS 200000
#define NUM_PRODUCTS 100000
#define N_NODES 300000
#define N_EDGES 1000000
#define EDIM 64
#define FDIM 128
#define CAP 40            // fixed adjacency capacity/node; max degree ~27 (Poisson(10) tail)
#define LDST 72           // LDS tile row stride in u16 (144 B: 16B-aligned, breaks pow2 banks)
#define NT_U 12500        // user tiles
#define NT_P 6250         // product tiles
#define NT_ALL 18750      // total node tiles
#define NBUK 625          // CSR bins: dest in [0,200000), 320 nodes/bucket (51.2KB stage in LDS)
#define BNODES 320
#define BINCAP 6144       // heavy bucket ~4800±120 (user+product dest overlap); +6sigma < 5520
#define ZERO_BLK 1175     // 1175*256 = 300800 >= 300032 cnt + 625 bucket counters
#define XC1_BLOCKS 1024   // persistent-wave grid for k_xform_c1
#define XC1_WAVES (XC1_BLOCKS * 4)   // 4096
#define XC1_UW 2731       // user waves (~ 4096 * 12500/18750); product waves = 1365

typedef __attribute__((ext_vector_type(8))) short short8;   // 8 bf16 in 4 VGPRs
typedef __attribute__((ext_vector_type(4))) float f32x4;    // MFMA accumulator

// fp32 -> bf16 round-to-nearest-even
static __device__ inline short f2bf(float f) {
    unsigned int u = __float_as_uint(f);
    unsigned int r = (u + 0x7FFFu + ((u >> 16) & 1u)) >> 16;
    return (short)r;
}
static __device__ inline float bf2f(unsigned short s) {
    return __uint_as_float(((unsigned int)s) << 16);
}
// deg^-1/2 with self-loop; same v_rsq_f32 the old k_dis used -> bit-identical numerics
static __device__ inline float disf(int c) {
    return rsqrtf(1.0f + (float)c);
}

// ---------------- setup: zero cnt + bucket counters + weight prep ----------------
// wts layout (shorts): WufT@0(8192) WpfT@8192(8192) c1T@16384(4096) c2T@20480(4096) W1T@24576(8192)
__global__ void k_setup(int* __restrict__ cnt,
                        const float* __restrict__ W_uf, const float* __restrict__ W_pf,
                        const float* __restrict__ c1, const float* __restrict__ c2,
                        const float* __restrict__ W1, short* __restrict__ wts) {
    int b = blockIdx.x;
    if (b < ZERO_BLK) {
        int i = b * 256 + threadIdx.x;
        if (i < 300032 + NBUK) cnt[i] = 0;   // cnt + gbin_cnt (contiguous)
        return;
    }
    int gid = (b - ZERO_BLK) * 256 + threadIdx.x;
    if (gid >= 32768) return;
    if (gid < 8192) {
        int n = gid >> 7, k = gid & 127;
        wts[gid] = f2bf(W_uf[k * 64 + n]);
    } else if (gid < 16384) {
        int i = gid - 8192; int n = i >> 7, k = i & 127;
        wts[gid] = f2bf(W_pf[k * 64 + n]);
    } else if (gid < 20480) {
        int i = gid - 16384; int n = i >> 6, k = i & 63;
        wts[gid] = f2bf(c1[k * 64 + n]);
    } else if (gid < 24576) {
        int i = gid - 20480; int n = i >> 6, k = i & 63;
        wts[gid] = f2bf(c2[k * 64 + n]);
    } else {
        int i = gid - 24576; int n = i >> 7, k = i & 127;
        wts[gid] = f2bf(W1[k * 64 + n]);
    }
}

// ---------------- CSR phase 1: LDS-binned edge scatter into per-bucket streams ----------------
__global__ __launch_bounds__(256) void k_bin(
    const int* __restrict__ ei, int* __restrict__ gcnt, int* __restrict__ gbin) {
    __shared__ int lcnt[NBUK];
    __shared__ int lbase[NBUK];
    int tid = threadIdx.x;
    for (int i = tid; i < NBUK; i += 256) lcnt[i] = 0;
    __syncthreads();
    int e0 = (blockIdx.x * 256 + tid) * 4;
    bool act = e0 < N_EDGES;
    int d[8], s[8], rk[8], bk[8];
    if (act) {
        int4 uu = *(const int4*)(ei + e0);            // user ids
        int4 pp = *(const int4*)(ei + N_EDGES + e0);  // raw (un-offset) product ids — reference quirk
        d[0] = pp.x; s[0] = uu.x;  d[1] = uu.x; s[1] = pp.x;
        d[2] = pp.y; s[2] = uu.y;  d[3] = uu.y; s[3] = pp.y;
        d[4] = pp.z; s[4] = uu.z;  d[5] = uu.z; s[5] = pp.z;
        d[6] = pp.w; s[6] = uu.w;  d[7] = uu.w; s[7] = pp.w;
#pragma unroll
        for (int j = 0; j < 8; ++j) {
            bk[j] = d[j] / BNODES;                    // dest < 200000 always
            rk[j] = atomicAdd(&lcnt[bk[j]], 1);
        }
    }
    __syncthreads();
    for (int i = tid; i < NBUK; i += 256) lbase[i] = atomicAdd(&gcnt[i], lcnt[i]);
    __syncthreads();
    if (act) {
#pragma unroll
        for (int j = 0; j < 8; ++j) {
            int pos = lbase[bk[j]] + rk[j];
            if (pos < BINCAP)                         // safety guard (expected max ~5.5K << 6144)
                *(int2*)(gbin + ((size_t)bk[j] * BINCAP + pos) * 2) = make_int2(d[j], s[j]);
        }
    }
}

// ---------------- CSR phase 2: LDS-staged per-bucket adjacency, coalesced write-out ----------------
// v2: the scatter lands in LDS (no L2 partial-line flushes — v1 wrote 86MB for 8MB useful).
// One block per bucket: LDS-atomic slot assign -> ds_write stage -> int4 blast to adj (full lines).
__global__ __launch_bounds__(256) void k_csr(
    const int* __restrict__ gcnt, const int* __restrict__ gbin,
    int* __restrict__ cnt, int* __restrict__ adj) {
    __shared__ int lcnt[BNODES];                       // 1.25 KB
    __shared__ __align__(16) int stage[BNODES * CAP];  // 51.2 KB
    int bucket = blockIdx.x;
    int base = bucket * BNODES;
    int tid = threadIdx.x;
    for (int i = tid; i < BNODES; i += 256) lcnt[i] = 0;
    __syncthreads();
    int n = gcnt[bucket];
    if (n > BINCAP) n = BINCAP;                        // matches k_bin drop guard
    const int* bb = gbin + (size_t)bucket * BINCAP * 2;
    for (int idx = tid; idx < n; idx += 256) {
        int2 e = *(const int2*)(bb + (size_t)idx * 2);
        int ln = e.x - base;
        int s = atomicAdd(&lcnt[ln], 1);               // LDS atomic: ~ns, no L2 round-trip
        stage[ln * CAP + s] = e.y;
    }
    __syncthreads();
    for (int i = tid; i < BNODES; i += 256) cnt[base + i] = lcnt[i];
    int4* dst = (int4*)(adj + (size_t)base * CAP);     // bucket region = 51.2KB, 16B-aligned
    const int4* src = (const int4*)stage;
#pragma unroll 4
    for (int i = tid; i < BNODES * CAP / 4; i += 256) dst[i] = src[i];  // unused slots = garbage, never read (cnt bounds)
}

// ---------------- FUSED: x0 = feat@W + b + emb; h1' = dis*(x0@c1W) ----------------
// v4: persistent waves + 2-stage software pipeline (cross-iteration loads are the pattern
// the scheduler keeps in flight; straight-line hoisting was re-sunk twice).
#define XC1_LOAD(S, MT) do {                                                         \
    int mb_ = (MT) * 16;                                                             \
    const float* ar_ = feat + (size_t)(mb_ + ln) * FDIM + quad * 8;                  \
    _Pragma("unroll")                                                                \
    for (int kk_ = 0; kk_ < 4; ++kk_) {                                              \
        fl##S[kk_] = *(const float4*)(ar_ + kk_ * 32);                               \
        fh##S[kk_] = *(const float4*)(ar_ + kk_ * 32 + 4);                           \
    }                                                                                \
    _Pragma("unroll")                                                                \
    for (int r_ = 0; r_ < 4; ++r_)                                                   \
        _Pragma("unroll")                                                            \
        for (int t_ = 0; t_ < 4; ++t_)                                               \
            ev##S[r_][t_] = emb[(size_t)(mb_ + quad * 4 + r_) * EDIM + t_ * 16 + ln];\
    _Pragma("unroll")                                                                \
    for (int r_ = 0; r_ < 4; ++r_)                                                   \
        cd##S[r_] = cnt[node_off + mb_ + quad * 4 + r_];                             \
} while (0)

#define XC1_COMPUTE(S, MT) do {                                                      \
    int mb_ = (MT) * 16;                                                             \
    f32x4 acc_[4] = {{0.f,0.f,0.f,0.f},{0.f,0.f,0.f,0.f},{0.f,0.f,0.f,0.f},{0.f,0.f,0.f,0.f}}; \
    _Pragma("unroll")                                                                \
    for (int kk_ = 0; kk_ < 4; ++kk_) {                                              \
        short8 Af_;                                                                  \
        Af_[0] = f2bf(fl##S[kk_].x); Af_[1] = f2bf(fl##S[kk_].y);                    \
        Af_[2] = f2bf(fl##S[kk_].z); Af_[3] = f2bf(fl##S[kk_].w);                    \
        Af_[4] = f2bf(fh##S[kk_].x); Af_[5] = f2bf(fh##S[kk_].y);                    \
        Af_[6] = f2bf(fh##S[kk_].z); Af_[7] = f2bf(fh##S[kk_].w);                    \
        _Pragma("unroll")                                                            \
        for (int t_ = 0; t_ < 4; ++t_)                                               \
            acc_[t_] = __builtin_amdgcn_mfma_f32_16x16x32_bf16(Af_, Bx[t_][kk_], acc_[t_], 0, 0, 0); \
    }                                                                                \
    _Pragma("unroll")                                                                \
    for (int r_ = 0; r_ < 4; ++r_)                                                   \
        _Pragma("unroll")                                                            \
        for (int t_ = 0; t_ < 4; ++t_) {                                             \
            float v_ = acc_[t_][r_] + bv[t_] + ev##S[r_][t_];                        \
            lds[wave][(quad * 4 + r_) * LDST + t_ * 16 + ln] = (unsigned short)f2bf(v_); \
        }                                                                            \
    f32x4 acch_[4] = {{0.f,0.f,0.f,0.f},{0.f,0.f,0.f,0.f},{0.f,0.f,0.f,0.f},{0.f,0.f,0.f,0.f}}; \
    _Pragma("unroll")                                                                \
    for (int kk_ = 0; kk_ < 2; ++kk_) {                                              \
        short8 Af_ = *(const short8*)(&lds[wave][ln * LDST + kk_ * 32 + quad * 8]);  \
        _Pragma("unroll")                                                            \
        for (int t_ = 0; t_ < 4; ++t_)                                               \
            acch_[t_] = __builtin_amdgcn_mfma_f32_16x16x32_bf16(Af_, Bc[t_][kk_], acch_[t_], 0, 0, 0); \
    }                                                                                \
    _Pragma("unroll")                                                                \
    for (int r_ = 0; r_ < 4; ++r_) {                                                 \
        float dv_ = disf(cd##S[r_]);                                                 \
        int node_ = mb_ + quad * 4 + r_;                                             \
        _Pragma("unroll")                                                            \
        for (int t_ = 0; t_ < 4; ++t_)                                               \
            h[(size_t)(node_off + node_) * EDIM + t_ * 16 + ln] =                    \
                (unsigned short)f2bf(dv_ * acch_[t_][r_]);                           \
    }                                                                                \
} while (0)

__global__ __launch_bounds__(256, 2) void k_xform_c1(
    const float* __restrict__ user_feat, const float* __restrict__ prod_feat,
    const short* __restrict__ wts,
    const float* __restrict__ b_uf, const float* __restrict__ b_pf,
    const float* __restrict__ user_emb, const float* __restrict__ prod_emb,
    const int* __restrict__ cnt, unsigned short* __restrict__ h) {
    __shared__ unsigned short lds[4][16 * LDST];
    int tid = threadIdx.x;
    int wave = tid >> 6;
    int lane = tid & 63, ln = lane & 15, quad = lane >> 4;
    int gw = blockIdx.x * 4 + wave;

    // wave-static operand selection: user waves [0,XC1_UW), product waves [XC1_UW,4096)
    const float* feat; const short* WT; const float* b; const float* emb;
    int node_off, t0, tcnt, tstride;
    if (gw < XC1_UW) {
        feat = user_feat; WT = wts;        b = b_uf; emb = user_emb;
        node_off = 0;         t0 = gw;          tcnt = NT_U; tstride = XC1_UW;
    } else {
        feat = prod_feat; WT = wts + 8192; b = b_pf; emb = prod_emb;
        node_off = NUM_USERS; t0 = gw - XC1_UW; tcnt = NT_P; tstride = XC1_WAVES - XC1_UW;
    }
    if (t0 >= tcnt) return;
    const short* c1T = wts + 16384;

    // loop-invariant weights (resident all iterations)
    short8 Bx[4][4];
#pragma unroll
    for (int t = 0; t < 4; ++t)
#pragma unroll
        for (int kk = 0; kk < 4; ++kk)
            Bx[t][kk] = *(const short8*)(WT + ((t * 16 + ln) * 128 + kk * 32 + quad * 8));
    short8 Bc[4][2];
#pragma unroll
    for (int t = 0; t < 4; ++t)
#pragma unroll
        for (int kk = 0; kk < 2; ++kk)
            Bc[t][kk] = *(const short8*)(c1T + ((t * 16 + ln) * 64 + kk * 32 + quad * 8));
    float bv[4];
#pragma unroll
    for (int t = 0; t < 4; ++t) bv[t] = b[t * 16 + ln];

    // two explicit pipeline stages (A/B named regs — no runtime-indexed buffers)
    float4 flA[4], fhA[4], flB[4], fhB[4];
    float evA[4][4], evB[4][4];
    int cdA[4], cdB[4];

    int t = t0;
    XC1_LOAD(A, t);
    for (;;) {
        int tn = t + tstride;
        bool hasB = tn < tcnt;
        if (hasB) XC1_LOAD(B, tn);       // next tile's loads in flight over current compute
        XC1_COMPUTE(A, t);
        if (!hasB) break;
        t = tn;
        tn = t + tstride;
        bool hasA = tn < tcnt;
        if (hasA) XC1_LOAD(A, tn);
        XC1_COMPUTE(B, t);
        if (!hasA) break;
        t = tn;
    }
}

// ---------------- FUSED: x1 = relu(dis*(h1'[d]+Σ h1'[src]) + b1); h2' = dis*(x1@c2W) ----------------
__global__ __launch_bounds__(256) void k_gather_c2(
    const int* __restrict__ adj, const int* __restrict__ cnt,
    const unsigned short* __restrict__ h,
    const float* __restrict__ b1, const short* __restrict__ c2T,
    unsigned short* __restrict__ hout) {
    __shared__ unsigned short lds[4][16 * LDST];
    int tid = threadIdx.x;
    int wave = tid >> 6;
    int tile = blockIdx.x * 4 + wave;
    if (tile >= N_NODES / 16) return;        // no barrier in kernel -> early exit safe
    int lane = tid & 63, ln = lane & 15, quad = lane >> 4;
    const unsigned int* hp = (const unsigned int*)h;    // bf16x2 view, row stride 32

    short8 Bc[4][2];
#pragma unroll
    for (int t = 0; t < 4; ++t)
#pragma unroll
        for (int kk = 0; kk < 2; ++kk)
            Bc[t][kk] = *(const short8*)(c2T + ((t * 16 + ln) * 64 + kk * 32 + quad * 8));

    int mbase = tile * 16;
    float2 bb0 = ((const float2*)b1)[ln];        // feats 2ln, 2ln+1
    float2 bb1 = ((const float2*)b1)[16 + ln];   // feats 32+2ln, 32+2ln+1

#pragma unroll 1
    for (int it = 0; it < 4; ++it) {
        int d = mbase + it * 4 + quad;
        const unsigned int* hrow = hp + (size_t)d * 32;
        unsigned int s0 = hrow[ln], s1 = hrow[16 + ln];          // self-loop term
        float a0 = bf2f((unsigned short)s0);
        float a1 = bf2f((unsigned short)(s0 >> 16));
        float a2 = bf2f((unsigned short)s1);
        float a3 = bf2f((unsigned short)(s1 >> 16));
        int cd = cnt[d];
        const int* ap = adj + (size_t)d * CAP;
        int i = 0;
        for (; i + 1 < cd; i += 2) {                             // 4 gathers in flight/lane
            int r0 = ap[i], r1 = ap[i + 1];
            unsigned int p00 = hp[(size_t)r0 * 32 + ln];
            unsigned int p01 = hp[(size_t)r0 * 32 + 16 + ln];
            unsigned int p10 = hp[(size_t)r1 * 32 + ln];
            unsigned int p11 = hp[(size_t)r1 * 32 + 16 + ln];
            a0 += bf2f((unsigned short)p00) + bf2f((unsigned short)p10);
            a1 += bf2f((unsigned short)(p00 >> 16)) + bf2f((unsigned short)(p10 >> 16));
            a2 += bf2f((unsigned short)p01) + bf2f((unsigned short)p11);
            a3 += bf2f((unsigned short)(p01 >> 16)) + bf2f((unsigned short)(p11 >> 16));
        }
        if (i < cd) {
            int r0 = ap[i];
            unsigned int p00 = hp[(size_t)r0 * 32 + ln];
            unsigned int p01 = hp[(size_t)r0 * 32 + 16 + ln];
            a0 += bf2f((unsigned short)p00);
            a1 += bf2f((unsigned short)(p00 >> 16));
            a2 += bf2f((unsigned short)p01);
            a3 += bf2f((unsigned short)(p01 >> 16));
        }
        float dv = disf(cd);
        float v0 = fmaxf(fmaf(dv, a0, bb0.x), 0.f);
        float v1 = fmaxf(fmaf(dv, a1, bb0.y), 0.f);
        float v2 = fmaxf(fmaf(dv, a2, bb1.x), 0.f);
        float v3 = fmaxf(fmaf(dv, a3, bb1.y), 0.f);
        unsigned int* lrow = (unsigned int*)&lds[wave][(it * 4 + quad) * LDST];
        lrow[ln] = ((unsigned int)(unsigned short)f2bf(v1) << 16)
                 | (unsigned int)(unsigned short)f2bf(v0);
        lrow[16 + ln] = ((unsigned int)(unsigned short)f2bf(v3) << 16)
                      | (unsigned int)(unsigned short)f2bf(v2);
    }
    // intra-wave LDS dependency only: no barrier needed
    // h2' = dis * (x1 @ c2W)
    f32x4 acc[4] = {{0.f,0.f,0.f,0.f},{0.f,0.f,0.f,0.f},{0.f,0.f,0.f,0.f},{0.f,0.f,0.f,0.f}};
#pragma unroll
    for (int kk = 0; kk < 2; ++kk) {
        short8 Af = *(const short8*)(&lds[wave][ln * LDST + kk * 32 + quad * 8]);
#pragma unroll
        for (int t = 0; t < 4; ++t)
            acc[t] = __builtin_amdgcn_mfma_f32_16x16x32_bf16(Af, Bc[t][kk], acc[t], 0, 0, 0);
    }
    float disv[4];
#pragma unroll
    for (int r = 0; r < 4; ++r) disv[r] = disf(cnt[mbase + quad * 4 + r]);
#pragma unroll
    for (int r = 0; r < 4; ++r) {
        int node = mbase + quad * 4 + r;
#pragma unroll
        for (int t = 0; t < 4; ++t)
            hout[(size_t)node * EDIM + t * 16 + ln] = (unsigned short)f2bf(disv[r] * acc[t][r]);
    }
}

// ---------------- gather + finish (conv2 output): x[d] = dis[d]*(h'[d]+Σ h'[src]) + b ----------------
__global__ __launch_bounds__(256) void k_gather(
    const int* __restrict__ adj, const int* __restrict__ cnt,
    const unsigned short* __restrict__ h,
    const float* __restrict__ b, unsigned short* __restrict__ xout, int relu) {
    int d = blockIdx.x * 4 + (threadIdx.x >> 6);
    if (d >= N_NODES) return;
    int l = threadIdx.x & 63;
    int half = l >> 5, c2 = l & 31;              // feature pair c2 -> feats {2c2, 2c2+1}
    const unsigned int* hp = (const unsigned int*)h;   // bf16x2 view, row stride 32

    float ax = 0.f, ay = 0.f;
    if (half == 0) {                              // self-loop term, counted once
        unsigned int pr = hp[(size_t)d * 32 + c2];
        ax = bf2f((unsigned short)pr);
        ay = bf2f((unsigned short)(pr >> 16));
    }
    int c = cnt[d];
    const int* ap = adj + (size_t)d * CAP;
    int i = 0;
    for (; i + 3 < c; i += 4) {
        int s0 = ap[i + half];
        int s1 = ap[i + 2 + half];
        unsigned int p0 = hp[(size_t)s0 * 32 + c2];
        unsigned int p1 = hp[(size_t)s1 * 32 + c2];
        ax += bf2f((unsigned short)p0) + bf2f((unsigned short)p1);
        ay += bf2f((unsigned short)(p0 >> 16)) + bf2f((unsigned short)(p1 >> 16));
    }
    if (i + half < c) {
        unsigned int p0 = hp[(size_t)ap[i + half] * 32 + c2];
        ax += bf2f((unsigned short)p0);
        ay += bf2f((unsigned short)(p0 >> 16));
    }
    if (i + 2 + half < c) {
        unsigned int p0 = hp[(size_t)ap[i + 2 + half] * 32 + c2];
        ax += bf2f((unsigned short)p0);
        ay += bf2f((unsigned short)(p0 >> 16));
    }
    ax += __shfl_xor(ax, 32, 64);                 // combine the two halves
    ay += __shfl_xor(ay, 32, 64);
    float dv = disf(c);
    float2 bb = ((const float2*)b)[c2];
    float v0 = fmaf(dv, ax, bb.x);
    float v1 = fmaf(dv, ay, bb.y);
    if (relu) { v0 = fmaxf(v0, 0.f); v1 = fmaxf(v1, 0.f); }
    if (half == 0) {
        unsigned int pk = ((unsigned int)(unsigned short)f2bf(v1) << 16)
                        | (unsigned int)(unsigned short)f2bf(v0);
        ((unsigned int*)xout)[(size_t)d * 32 + c2] = pk;
    }
}

// ---------------- edge predictor via bf16 MFMA, ei prefetch + hoisted A loads ----------------
__global__ __launch_bounds__(256) void k_pred_mfma(
    const int* __restrict__ ei, const unsigned short* __restrict__ x,
    const short* __restrict__ W1T, const float* __restrict__ b1,
    const float* __restrict__ W2, const float* __restrict__ b2,
    float* __restrict__ preds) {
    int tid = threadIdx.x;
    int wave = tid >> 6, lane = tid & 63;
    int ln = lane & 15, quad = lane >> 4;

    short8 Bf[4][4];
#pragma unroll
    for (int t = 0; t < 4; ++t)
#pragma unroll
        for (int kk = 0; kk < 4; ++kk)
            Bf[t][kk] = *(const short8*)(W1T + ((t * 16 + ln) * 128 + kk * 32 + quad * 8));

    float b1v[4], W2v[4];
#pragma unroll
    for (int t = 0; t < 4; ++t) {
        b1v[t] = b1[t * 16 + ln];
        W2v[t] = W2[t * 16 + ln];
    }
    float b2s = b2[0];

    const int n_tiles = N_EDGES / 16;
    int gw = blockIdx.x * 4 + wave;
    int nwaves = gridDim.x * 4;

    int cu = 0, cp = 0;
    if (gw < n_tiles) {
        cu = ei[gw * 16 + ln];
        cp = ei[N_EDGES + gw * 16 + ln] + NUM_USERS;
    }
    for (int tile = gw; tile < n_tiles; tile += nwaves) {
        int u = cu, p = cp;
        int nt = tile + nwaves;
        if (nt < n_tiles) {                       // prefetch next tile's indices
            cu = ei[nt * 16 + ln];
            cp = ei[N_EDGES + nt * 16 + ln] + NUM_USERS;
        }
        short8 Af[4];                             // all 4 A loads in flight
        Af[0] = *(const short8*)(x + (size_t)u * EDIM + quad * 8);
        Af[1] = *(const short8*)(x + (size_t)u * EDIM + 32 + quad * 8);
        Af[2] = *(const short8*)(x + (size_t)p * EDIM + quad * 8);
        Af[3] = *(const short8*)(x + (size_t)p * EDIM + 32 + quad * 8);

        f32x4 acc[4] = {{0.f,0.f,0.f,0.f},{0.f,0.f,0.f,0.f},{0.f,0.f,0.f,0.f},{0.f,0.f,0.f,0.f}};
#pragma unroll
        for (int kk = 0; kk < 4; ++kk)
#pragma unroll
            for (int t = 0; t < 4; ++t)
                acc[t] = __builtin_amdgcn_mfma_f32_16x16x32_bf16(Af[kk], Bf[t][kk], acc[t], 0, 0, 0);

        float out[4];
#pragma unroll
        for (int r = 0; r < 4; ++r) {
            float part = 0.f;
#pragma unroll
            for (int t = 0; t < 4; ++t) {
                float hv = fmaxf(acc[t][r] + b1v[t], 0.f);
                part = fmaf(hv, W2v[t], part);
            }
            part += __shfl_xor(part, 1, 64);
            part += __shfl_xor(part, 2, 64);
            part += __shfl_xor(part, 4, 64);
            part += __shfl_xor(part, 8, 64);
            out[r] = part;
        }
        if (ln == 0) {
            int ebase = tile * 16;
#pragma unroll
            for (int r = 0; r < 4; ++r) {
                float logit = out[r] + b2s;
                preds[ebase + quad * 4 + r] = 5.f / (1.f + expf(-logit));
            }
        }
    }
}

extern "C" void kernel_launch(void* const* d_in, const int* in_sizes, int n_in,
                              void* d_out, int out_size, void* d_ws, size_t ws_size,
                              hipStream_t stream) {
    const int*   ei        = (const int*)d_in[0];
    const float* user_feat = (const float*)d_in[1];
    const float* prod_feat = (const float*)d_in[2];
    const float* user_emb  = (const float*)d_in[3];
    const float* prod_emb  = (const float*)d_in[4];
    const float* W_uf      = (const float*)d_in[5];
    const float* b_uf      = (const float*)d_in[6];
    const float* W_pf      = (const float*)d_in[7];
    const float* b_pf      = (const float*)d_in[8];
    const float* conv1_W   = (const float*)d_in[9];
    const float* conv1_b   = (const float*)d_in[10];
    const float* conv2_W   = (const float*)d_in[11];
    const float* conv2_b   = (const float*)d_in[12];
    const float* pred_W1   = (const float*)d_in[13];
    const float* pred_b1   = (const float*)d_in[14];
    const float* pred_W2   = (const float*)d_in[15];
    const float* pred_b2   = (const float*)d_in[16];

    // workspace layout (4-byte units)
    int* ws_i = (int*)d_ws;
    int*   cnt  = ws_i;                            // 300032 + NBUK bucket counters right after
    int*   gcnt = ws_i + 300032;                   // 625 ints (zeroed with cnt)
    int*   adj  = ws_i + 600064;                   // 300032*40 = 12,001,280
    unsigned short* xbuf = (unsigned short*)(ws_i + 12601344);  // 38.4MB; gbin overlays (dead until gather_c2)
    int*   gbin = ws_i + 12601344;                 // 625*6144 int2 entries = 30.7MB
    unsigned short* hbuf = (unsigned short*)(ws_i + 22201344);  // 38.4MB
    short* wts = (short*)(ws_i + 31801344);        // 32768 bf16
    float* preds = (float*)d_out;

    // setup (zero cnt+gcnt + weight prep), then two-phase binned CSR build
    k_setup<<<ZERO_BLK + 128, 256, 0, stream>>>(cnt, W_uf, W_pf, conv1_W, conv2_W, pred_W1, wts);
    k_bin<<<(N_EDGES / 4 + 255) / 256, 256, 0, stream>>>(ei, gcnt, gbin);
    k_csr<<<NBUK, 256, 0, stream>>>(gcnt, gbin, cnt, adj);

    // fused node-transform + conv1 GEMM (persistent waves, 2-stage pipeline) -> hbuf = h1'
    k_xform_c1<<<XC1_BLOCKS, 256, 0, stream>>>(user_feat, prod_feat, wts,
                                               b_uf, b_pf, user_emb, prod_emb,
                                               cnt, hbuf);

    // fused conv1-gather + conv2 GEMM -> xbuf = h2' (gbin dead from here); x1 never hits memory
    k_gather_c2<<<(18750 + 3) / 4, 256, 0, stream>>>(adj, cnt, hbuf, conv1_b,
                                                     wts + 20480, xbuf);
    // conv2 gather -> hbuf = x2 (final node embeddings)
    k_gather<<<N_NODES / 4, 256, 0, stream>>>(adj, cnt, xbuf, conv2_b, hbuf, 0);

    // predictor
    k_pred_mfma<<<2048, 256, 0, stream>>>(ei, hbuf, wts + 24576, pred_b1, pred_W2, pred_b2, preds);
}